// Round 3
// baseline (1086.733 us; speedup 1.0000x reference)
//
#include <hip/hip_runtime.h>
#include <cstdint>
#include <cstddef>

#define N_TOK 8192
#define DIM   1024
#define HID   4096
#define DOUT  1024
#define NEXP  8
#define BM 256
#define BN 256

typedef short  s16x8 __attribute__((ext_vector_type(8)));
typedef __bf16 b16x8 __attribute__((ext_vector_type(8)));
typedef float  f32x4 __attribute__((ext_vector_type(4)));

__device__ __forceinline__ unsigned short f2bf(float f) {
  unsigned u = __float_as_uint(f);
  u += 0x7fffu + ((u >> 16) & 1u);
  return (unsigned short)(u >> 16);
}

__device__ __forceinline__ float gelu_f(float v) {
  return 0.5f * v * (1.0f + erff(v * 0.70710678118654752440f));
}

// async global->LDS, 16B per lane. LDS dest wave-uniform base; HW writes
// lane i at base + i*16. Global src is per-lane (enables source pre-swizzle).
__device__ __forceinline__ void gl_lds16(const void* g, void* l) {
  auto gp = (__attribute__((address_space(1))) void*)(reinterpret_cast<uintptr_t>(g));
  auto lp = (__attribute__((address_space(3))) void*)(reinterpret_cast<uintptr_t>(l));
  __builtin_amdgcn_global_load_lds(gp, lp, 16, 0, 0);
}

// ---------------- small kernels ----------------

__global__ void init_kernel(int* counts) {
  if (threadIdx.x < NEXP) counts[threadIdx.x] = 0;
}

__global__ void cast_x_kernel(const float* __restrict__ src,
                              unsigned short* __restrict__ dst) {
  int i = blockIdx.x * 256 + threadIdx.x;
  float4 v = reinterpret_cast<const float4*>(src)[i];
  ushort4 o;
  o.x = f2bf(v.x); o.y = f2bf(v.y); o.z = f2bf(v.z); o.w = f2bf(v.w);
  reinterpret_cast<ushort4*>(dst)[i] = o;
}

// src [R][C] f32 (batched by blockIdx.z) -> dst [C][R] bf16
__global__ void transpose_cast_kernel(const float* __restrict__ src,
                                      unsigned short* __restrict__ dst,
                                      int R, int C) {
  __shared__ float tile[32][33];
  size_t base = (size_t)blockIdx.z * (size_t)R * (size_t)C;
  src += base; dst += base;
  int c0 = blockIdx.x * 32, r0 = blockIdx.y * 32;
  int tx = threadIdx.x, ty = threadIdx.y;  // 32 x 8
#pragma unroll
  for (int i = 0; i < 4; ++i)
    tile[ty + 8 * i][tx] = src[(size_t)(r0 + ty + 8 * i) * C + (c0 + tx)];
  __syncthreads();
#pragma unroll
  for (int i = 0; i < 4; ++i)
    dst[(size_t)(c0 + ty + 8 * i) * R + (r0 + tx)] = f2bf(tile[tx][ty + 8 * i]);
}

// one wave per token: f32 gate logits, top-2, renormalized weights
__global__ void gate_kernel(const float* __restrict__ x,
                            const float* __restrict__ gw,
                            int* __restrict__ topk_e,
                            float* __restrict__ topk_w,
                            int* __restrict__ counts) {
  int w = threadIdx.x >> 6, lane = threadIdx.x & 63;
  int t = blockIdx.x * 4 + w;
  const float* xr = x + (size_t)t * DIM;
  float acc[8];
#pragma unroll
  for (int e = 0; e < 8; ++e) acc[e] = 0.f;
  for (int i = 0; i < DIM / 64; ++i) {
    int d = lane + (i << 6);
    float xv = xr[d];
    float4 g0 = *reinterpret_cast<const float4*>(gw + (size_t)d * 8);
    float4 g1 = *reinterpret_cast<const float4*>(gw + (size_t)d * 8 + 4);
    acc[0] += xv * g0.x; acc[1] += xv * g0.y; acc[2] += xv * g0.z; acc[3] += xv * g0.w;
    acc[4] += xv * g1.x; acc[5] += xv * g1.y; acc[6] += xv * g1.z; acc[7] += xv * g1.w;
  }
#pragma unroll
  for (int o = 32; o; o >>= 1)
#pragma unroll
    for (int e = 0; e < 8; ++e) acc[e] += __shfl_down(acc[e], o);
  if (lane == 0) {
    int e0 = 0;
#pragma unroll
    for (int e = 1; e < 8; ++e) if (acc[e] > acc[e0]) e0 = e;
    int e1 = -1;
#pragma unroll
    for (int e = 0; e < 8; ++e) {
      if (e == e0) continue;
      if (e1 < 0 || acc[e] > acc[e1]) e1 = e;
    }
    float w0 = 1.0f / (1.0f + expf(acc[e1] - acc[e0]));  // == p0/(p0+p1)
    topk_e[t * 2 + 0] = e0;
    topk_e[t * 2 + 1] = e1;
    topk_w[t * 2 + 0] = w0;
    topk_w[t * 2 + 1] = 1.0f - w0;
    atomicAdd(&counts[e0], 1);
    atomicAdd(&counts[e1], 1);
  }
}

__global__ void offsets_kernel(const int* __restrict__ counts,
                               int* __restrict__ offsets,
                               int* __restrict__ cursor) {
  if (threadIdx.x == 0) {
    int o = 0;
    for (int e = 0; e < NEXP; ++e) {
      offsets[e] = o; cursor[e] = o; o += counts[e];
    }
    offsets[NEXP] = o;
  }
}

__global__ void scatter_kernel(const int* __restrict__ topk_e,
                               int* __restrict__ cursor,
                               int* __restrict__ rowmap,
                               int* __restrict__ inv) {
  int t = blockIdx.x * 256 + threadIdx.x;
#pragma unroll
  for (int s = 0; s < 2; ++s) {
    int e = topk_e[t * 2 + s];
    int p = atomicAdd(&cursor[e], 1);
    rowmap[p] = t * 2 + s;
    inv[t * 2 + s] = p;
  }
}

// ---------------- 8-phase MFMA GEMM (256x256 tile, BK=64 as 2x K32) -------
// C[M x Ncols] = A[. x K] * Bt[Ncols x K], both K-contiguous rows.
// 8 waves (2M x 4N), per-wave 128x64 output, acc[8][4] f32x4.
// LDS: 2 bufs x 4 parts {Ak0,Ak1,Bk0,Bk1}, each [256][32] bf16 = 16KB; 128KB.
// Per phase: {4|8 ds_read_b128, 1 half-tile stage (2 gl_lds), [vmcnt(4) at
// ph4/ph8], s_barrier, 16 MFMA (sched_barrier-pinned, setprio), s_barrier}.
// Stage stagger (ledger-verified): ph1:buf1.Ak1<-T(2t+1), ph2:buf1.Bk1,
// ph3..6: buf0.{Ak0,Bk0,Ak1,Bk1}<-T(2t+2), ph7,8: buf1.{Ak0,Bk0}<-T(2t+3).
// Each stage is >=1 barrier after the slot's last read; each read covered by
// the preceding vmcnt(4)+barrier. vmcnt never drains to 0 in the loop (T4).
// LDS XOR-swizzle: phys chunk = logical chunk ^ ((row>>1)&3), applied via
// pre-swizzled global source (gl_lds writes linearly) + swizzled ds_read.
// MODE 0: expert GEMM1, gathered A rows, epi: h = gelu(acc+b1) -> bf16
// MODE 1: expert GEMM2, compact A (h), epi: fOut[slot] = w*(acc+b2)  (f32)
// MODE 2: shared GEMM, dense, epi: fOut = 0.5*gelu(acc+b)            (f32)
template <int MODE>
__global__ __launch_bounds__(512, 2) void gemm_mfma(
    const unsigned short* __restrict__ A,
    const unsigned short* __restrict__ Ball,
    const float* __restrict__ biasAll,
    unsigned short* __restrict__ hOut,
    float* __restrict__ fOut,
    const int* __restrict__ rowmap,
    const int* __restrict__ offsets,
    const float* __restrict__ topkw,
    int K, int Ncols, int M2, int MT, int NT) {
  // T1: XCD-chunked bijective swizzle (grids are multiples of 8); mt-fastest
  // so consecutive blocks on one XCD share a B-panel (and expert).
  int nwg = gridDim.x;
  int bid = blockIdx.x;
  int lg = (bid & 7) * (nwg >> 3) + (bid >> 3);

  int e, mt, nt, rowBase, cnt;
  if (MODE == 2) {
    e = 0; rowBase = 0; cnt = M2;
    nt = lg / MT; mt = lg % MT;
  } else {
    int per = MT * NT;
    e = lg / per;
    int rem = lg % per;
    nt = rem / MT; mt = rem % MT;
    rowBase = offsets[e];
    cnt = offsets[e + 1] - rowBase;
    if (mt * BM >= cnt) return;
  }
  const unsigned short* B = Ball + (size_t)e * Ncols * K;
  const float* bias = biasAll + (size_t)e * Ncols;

  int t = threadIdx.x;
  int w = t >> 6, lane = t & 63;
  int wm = w >> 2, wn = w & 3;
  int fr = lane & 15, fg = lane >> 4;

  // [buf][part][256*32]  part: 0=Ak0 1=Ak1 2=Bk0 3=Bk1
  __shared__ __attribute__((aligned(16))) unsigned short lds[2][4][8192];

  // staging: thread t covers phys row (t>>2) [+128 for 2nd issue], phys
  // chunk t&3; logical (global) chunk = phys ^ ((row>>1)&3).
  int lc = (t & 3) ^ ((t >> 3) & 3);
  const unsigned short *aG0, *aG1, *bG0, *bG1;
  {
    int pr = t >> 2;
    size_t ar0, ar1;
    if (MODE == 2) {
      ar0 = (size_t)(mt * BM + pr);
      ar1 = ar0 + 128;
    } else {
      int g0 = mt * BM + pr, g1 = g0 + 128;
      int c0 = g0 < cnt ? g0 : cnt - 1;
      int c1 = g1 < cnt ? g1 : cnt - 1;
      if (MODE == 0) {
        ar0 = (size_t)(rowmap[rowBase + c0] >> 1);
        ar1 = (size_t)(rowmap[rowBase + c1] >> 1);
      } else {
        ar0 = (size_t)(rowBase + c0);
        ar1 = (size_t)(rowBase + c1);
      }
    }
    aG0 = A + ar0 * (size_t)K + lc * 8;
    aG1 = A + ar1 * (size_t)K + lc * 8;
    bG0 = B + (size_t)(nt * BN + pr) * K + lc * 8;
    bG1 = bG0 + (size_t)128 * K;
  }

#define STAGE_A(BUF, KH, KT)                                                  \
  {                                                                           \
    int _ko = (KT) * 64 + (KH) * 32;                                          \
    unsigned short* _dp = &lds[BUF][KH][0] + (w << 9);                        \
    gl_lds16(aG0 + _ko, _dp);                                                 \
    gl_lds16(aG1 + _ko, _dp + 4096);                                          \
  }
#define STAGE_B(BUF, KH, KT)                                                  \
  {                                                                           \
    int _ko = (KT) * 64 + (KH) * 32;                                          \
    unsigned short* _dp = &lds[BUF][2 + (KH)][0] + (w << 9);                  \
    gl_lds16(bG0 + _ko, _dp);                                                 \
    gl_lds16(bG1 + _ko, _dp + 4096);                                          \
  }

  // fragment read offsets (elements) inside a part; row stride 32 elements.
  int swc = fg ^ ((fr >> 1) & 3);
  int aoff = (wm * 128 + fr) * 32 + swc * 8;
  int boff = (wn * 64 + fr) * 32 + swc * 8;

  f32x4 acc[8][4] = {};

#define MF(M, AV, N)                                                          \
  acc[M][N] = __builtin_amdgcn_mfma_f32_16x16x32_bf16(                        \
      __builtin_bit_cast(b16x8, AV), __builtin_bit_cast(b16x8, b##N),         \
      acc[M][N], 0, 0, 0)

#define PHASE(BUF, KH, CH, DOSTAGE, DOVM)                                     \
  {                                                                           \
    const unsigned short* _ap = &lds[BUF][KH][0] + aoff;                      \
    const unsigned short* _bp = &lds[BUF][2 + (KH)][0] + boff;                \
    s16x8 a0 = *(const s16x8*)(_ap + ((CH)*4 + 0) * 512);                     \
    s16x8 a1 = *(const s16x8*)(_ap + ((CH)*4 + 1) * 512);                     \
    s16x8 a2 = *(const s16x8*)(_ap + ((CH)*4 + 2) * 512);                     \
    s16x8 a3 = *(const s16x8*)(_ap + ((CH)*4 + 3) * 512);                     \
    if ((CH) == 0) {                                                          \
      b0 = *(const s16x8*)(_bp + 0 * 512);                                    \
      b1 = *(const s16x8*)(_bp + 1 * 512);                                    \
      b2 = *(const s16x8*)(_bp + 2 * 512);                                    \
      b3 = *(const s16x8*)(_bp + 3 * 512);                                    \
    }                                                                         \
    DOSTAGE;                                                                  \
    if (DOVM) asm volatile("s_waitcnt vmcnt(4)" ::: "memory");                \
    asm volatile("s_barrier" ::: "memory");                                   \
    __builtin_amdgcn_sched_barrier(0);                                        \
    __builtin_amdgcn_s_setprio(1);                                            \
    MF((CH)*4 + 0, a0, 0); MF((CH)*4 + 0, a0, 1);                             \
    MF((CH)*4 + 0, a0, 2); MF((CH)*4 + 0, a0, 3);                             \
    MF((CH)*4 + 1, a1, 0); MF((CH)*4 + 1, a1, 1);                             \
    MF((CH)*4 + 1, a1, 2); MF((CH)*4 + 1, a1, 3);                             \
    MF((CH)*4 + 2, a2, 0); MF((CH)*4 + 2, a2, 1);                             \
    MF((CH)*4 + 2, a2, 2); MF((CH)*4 + 2, a2, 3);                             \
    MF((CH)*4 + 3, a3, 0); MF((CH)*4 + 3, a3, 1);                             \
    MF((CH)*4 + 3, a3, 2); MF((CH)*4 + 3, a3, 3);                             \
    __builtin_amdgcn_s_setprio(0);                                            \
    __builtin_amdgcn_sched_barrier(0);                                        \
    asm volatile("s_barrier" ::: "memory");                                   \
  }

  int KT = K >> 6;   // BK=64 tiles
  int NIT = K >> 7;  // loop iterations (2 tiles each); K % 128 == 0

  // prologue: buf0 <- T0 (all 4 parts), buf1.{Ak0,Bk0} <- T1.
  STAGE_A(0, 0, 0); STAGE_B(0, 0, 0); STAGE_A(0, 1, 0); STAGE_B(0, 1, 0);
  STAGE_A(1, 0, 1); STAGE_B(1, 0, 1);
  asm volatile("s_waitcnt vmcnt(4)" ::: "memory");  // buf0 fully landed
  asm volatile("s_barrier" ::: "memory");

  for (int it = 0; it < NIT; ++it) {
    int t2 = it * 2;
    int k2 = t2 + 2 < KT ? t2 + 2 : KT - 1;  // clamp: tail re-stages last tile
    int k3 = t2 + 3 < KT ? t2 + 3 : KT - 1;  // (loads valid, data unused)
    s16x8 b0, b1, b2, b3;
    PHASE(0, 0, 0, STAGE_A(1, 1, t2 + 1), 0);
    PHASE(0, 0, 1, STAGE_B(1, 1, t2 + 1), 0);
    PHASE(0, 1, 0, STAGE_A(0, 0, k2), 0);
    PHASE(0, 1, 1, STAGE_B(0, 0, k2), 1);
    PHASE(1, 0, 0, STAGE_A(0, 1, k2), 0);
    PHASE(1, 0, 1, STAGE_B(0, 1, k2), 0);
    PHASE(1, 1, 0, STAGE_A(1, 0, k3), 0);
    PHASE(1, 1, 1, STAGE_B(1, 0, k3), 1);
  }
#undef PHASE
#undef MF
#undef STAGE_A
#undef STAGE_B

  // ---- epilogue: C/D layout col=lane&15, row=(lane>>4)*4+q
  if (MODE == 0) {
#pragma unroll
    for (int n = 0; n < 4; ++n) {
      int col = nt * BN + wn * 64 + n * 16 + fr;
      float bc = bias[col];
#pragma unroll
      for (int m = 0; m < 8; ++m) {
#pragma unroll
        for (int q = 0; q < 4; ++q) {
          int r = mt * BM + wm * 128 + m * 16 + fg * 4 + q;
          if (r < cnt)
            hOut[(size_t)(rowBase + r) * (size_t)Ncols + col] =
                f2bf(gelu_f(acc[m][n][q] + bc));
        }
      }
    }
  } else if (MODE == 1) {
    int cols[4];
    float bc[4];
#pragma unroll
    for (int n = 0; n < 4; ++n) {
      cols[n] = nt * BN + wn * 64 + n * 16 + fr;
      bc[n] = bias[cols[n]];
    }
#pragma unroll
    for (int m = 0; m < 8; ++m) {
#pragma unroll
      for (int q = 0; q < 4; ++q) {
        int r = mt * BM + wm * 128 + m * 16 + fg * 4 + q;
        if (r < cnt) {
          float wgt = topkw[rowmap[rowBase + r]];
          float* orow = fOut + (size_t)(rowBase + r) * (size_t)Ncols;
#pragma unroll
          for (int n = 0; n < 4; ++n)
            orow[cols[n]] = wgt * (acc[m][n][q] + bc[n]);
        }
      }
    }
  } else {
#pragma unroll
    for (int n = 0; n < 4; ++n) {
      int col = nt * BN + wn * 64 + n * 16 + fr;
      float bc = bias[col];
#pragma unroll
      for (int m = 0; m < 8; ++m) {
#pragma unroll
        for (int q = 0; q < 4; ++q) {
          int r = mt * BM + wm * 128 + m * 16 + fg * 4 + q;
          fOut[(size_t)r * (size_t)Ncols + col] = 0.5f * gelu_f(acc[m][n][q] + bc);
        }
      }
    }
  }
}

// ---------------- LayerNorm (gathers shared + 2 expert slots) ----------------
__global__ void ln_kernel(const float* __restrict__ sh,
                          const float* __restrict__ acc2,
                          const int* __restrict__ inv,
                          const float* __restrict__ gamma,
                          const float* __restrict__ beta,
                          float* __restrict__ out) {
  int t = blockIdx.x, tid = threadIdx.x;
  int i0 = inv[t * 2 + 0], i1 = inv[t * 2 + 1];
  float4 a  = reinterpret_cast<const float4*>(sh   + (size_t)t  * DOUT)[tid];
  float4 c0 = reinterpret_cast<const float4*>(acc2 + (size_t)i0 * DOUT)[tid];
  float4 c1 = reinterpret_cast<const float4*>(acc2 + (size_t)i1 * DOUT)[tid];
  float4 v;
  v.x = a.x + c0.x + c1.x;
  v.y = a.y + c0.y + c1.y;
  v.z = a.z + c0.z + c1.z;
  v.w = a.w + c0.w + c1.w;
  float s = v.x + v.y + v.z + v.w;
  float q = v.x * v.x + v.y * v.y + v.z * v.z + v.w * v.w;
#pragma unroll
  for (int o = 32; o; o >>= 1) {
    s += __shfl_down(s, o);
    q += __shfl_down(q, o);
  }
  __shared__ float ss[4], sq[4];
  int w = tid >> 6, lane = tid & 63;
  if (lane == 0) { ss[w] = s; sq[w] = q; }
  __syncthreads();
  float S = ss[0] + ss[1] + ss[2] + ss[3];
  float Q = sq[0] + sq[1] + sq[2] + sq[3];
  float mean = S * (1.0f / DOUT);
  float var = Q * (1.0f / DOUT) - mean * mean;
  float inv_std = rsqrtf(var + 1e-5f);
  float4 g = reinterpret_cast<const float4*>(gamma)[tid];
  float4 b = reinterpret_cast<const float4*>(beta)[tid];
  float4 o;
  o.x = (v.x - mean) * inv_std * g.x + b.x;
  o.y = (v.y - mean) * inv_std * g.y + b.y;
  o.z = (v.z - mean) * inv_std * g.z + b.z;
  o.w = (v.w - mean) * inv_std * g.w + b.w;
  reinterpret_cast<float4*>(out + (size_t)t * DOUT)[tid] = o;
}

// ---------------- host ----------------
extern "C" void kernel_launch(void* const* d_in, const int* in_sizes, int n_in,
                              void* d_out, int out_size, void* d_ws, size_t ws_size,
                              hipStream_t stream) {
  const float* x       = (const float*)d_in[0];
  const float* W1      = (const float*)d_in[1];
  const float* b1      = (const float*)d_in[2];
  const float* W2      = (const float*)d_in[3];
  const float* b2      = (const float*)d_in[4];
  const float* gateW   = (const float*)d_in[5];
  const float* sharedW = (const float*)d_in[6];
  const float* sharedB = (const float*)d_in[7];
  const float* gamma   = (const float*)d_in[8];
  const float* beta    = (const float*)d_in[9];
  float* out = (float*)d_out;

  char* ws = (char*)d_ws;
  size_t off = 0;
  auto alloc = [&](size_t bytes) -> void* {
    void* p = ws + off;
    off += (bytes + 255) & ~(size_t)255;
    return p;
  };
  int*   counts = (int*)alloc(NEXP * 4);
  int*   offs   = (int*)alloc((NEXP + 1) * 4);
  int*   cursor = (int*)alloc(NEXP * 4);
  int*   topk_e = (int*)alloc((size_t)N_TOK * 2 * 4);
  float* topk_w = (float*)alloc((size_t)N_TOK * 2 * 4);
  int*   rowmap = (int*)alloc((size_t)N_TOK * 2 * 4);
  int*   inv    = (int*)alloc((size_t)N_TOK * 2 * 4);
  unsigned short* xbf  = (unsigned short*)alloc((size_t)N_TOK * DIM * 2);
  unsigned short* W1t  = (unsigned short*)alloc((size_t)NEXP * HID * DIM * 2);
  unsigned short* W2t  = (unsigned short*)alloc((size_t)NEXP * DOUT * HID * 2);
  unsigned short* sWt  = (unsigned short*)alloc((size_t)DOUT * DIM * 2);
  unsigned short* hbuf = (unsigned short*)alloc((size_t)N_TOK * 2 * HID * 2);
  float* acc2 = (float*)alloc((size_t)N_TOK * 2 * DOUT * 4);
  // shbuf aliases W1t's storage (W1t is dead after GEMM1; shared GEMM runs after)
  float* shbuf = (float*)W1t;
  if (off > ws_size) return;  // workspace too small -> fail validation loudly

  init_kernel<<<1, 64, 0, stream>>>(counts);
  cast_x_kernel<<<N_TOK * DIM / 1024, 256, 0, stream>>>(x, xbf);
  transpose_cast_kernel<<<dim3(HID / 32, DIM / 32, NEXP), dim3(32, 8), 0, stream>>>(W1, W1t, DIM, HID);
  transpose_cast_kernel<<<dim3(DOUT / 32, HID / 32, NEXP), dim3(32, 8), 0, stream>>>(W2, W2t, HID, DOUT);
  transpose_cast_kernel<<<dim3(DOUT / 32, DIM / 32, 1), dim3(32, 8), 0, stream>>>(sharedW, sWt, DIM, DOUT);
  gate_kernel<<<N_TOK / 4, 256, 0, stream>>>(x, gateW, topk_e, topk_w, counts);
  offsets_kernel<<<1, 64, 0, stream>>>(counts, offs, cursor);
  scatter_kernel<<<N_TOK / 256, 256, 0, stream>>>(topk_e, cursor, rowmap, inv);

  // GEMM1: h = gelu(x @ W1 + b1); MT=16 covers cnt<=4096/expert
  gemm_mfma<0><<<NEXP * 16 * (HID / BN), 512, 0, stream>>>(
      xbf, W1t, b1, hbuf, nullptr, rowmap, offs, topk_w, DIM, HID, 0, 16, HID / BN);
  // shared: shbuf = 0.5*gelu(x @ sharedW + sb)
  gemm_mfma<2><<<(N_TOK / BM) * (DOUT / BN), 512, 0, stream>>>(
      xbf, sWt, sharedB, nullptr, shbuf, nullptr, nullptr, nullptr, DIM, DOUT,
      N_TOK, N_TOK / BM, DOUT / BN);
  // GEMM2: acc2[slot] = w * (h @ W2 + b2)   (compact, no atomics)
  gemm_mfma<1><<<NEXP * 16 * (DOUT / BN), 512, 0, stream>>>(
      hbuf, W2t, b2, nullptr, acc2, rowmap, offs, topk_w, HID, DOUT, 0, 16, DOUT / BN);
  // LayerNorm(shared + slot0 + slot1) -> out
  ln_kernel<<<N_TOK, 256, 0, stream>>>(shbuf, acc2, inv, gamma, beta, out);
}

// Round 4
// 845.525 us; speedup vs baseline: 1.2853x; 1.2853x over previous
//
#include <hip/hip_runtime.h>
#include <cstdint>
#include <cstddef>

#define N_TOK 8192
#define DIM   1024
#define HID   4096
#define DOUT  1024
#define NEXP  8

typedef short  s16x8 __attribute__((ext_vector_type(8)));
typedef __bf16 b16x8 __attribute__((ext_vector_type(8)));
typedef float  f32x4 __attribute__((ext_vector_type(4)));

__device__ __forceinline__ unsigned short f2bf(float f) {
  unsigned u = __float_as_uint(f);
  u += 0x7fffu + ((u >> 16) & 1u);
  return (unsigned short)(u >> 16);
}

__device__ __forceinline__ float gelu_f(float v) {
  return 0.5f * v * (1.0f + erff(v * 0.70710678118654752440f));
}

// async global->LDS, 16B per lane. LDS dest wave-uniform base; HW writes
// lane i at base + i*16. Global src is per-lane.
__device__ __forceinline__ void gl_lds16(const void* g, void* l) {
  auto gp = (__attribute__((address_space(1))) void*)(reinterpret_cast<uintptr_t>(g));
  auto lp = (__attribute__((address_space(3))) void*)(reinterpret_cast<uintptr_t>(l));
  __builtin_amdgcn_global_load_lds(gp, lp, 16, 0, 0);
}

// ---------------- small kernels ----------------

__global__ void init_kernel(int* counts) {
  if (threadIdx.x < NEXP) counts[threadIdx.x] = 0;
}

__global__ void cast_x_kernel(const float* __restrict__ src,
                              unsigned short* __restrict__ dst) {
  int i = blockIdx.x * 256 + threadIdx.x;
  float4 v = reinterpret_cast<const float4*>(src)[i];
  ushort4 o;
  o.x = f2bf(v.x); o.y = f2bf(v.y); o.z = f2bf(v.z); o.w = f2bf(v.w);
  reinterpret_cast<ushort4*>(dst)[i] = o;
}

// src [R][C] f32 (batched by blockIdx.z) -> dst [C][R] bf16.
// 64x64 tile; float4 reads, ushort4 writes (full 128B lines per dst row).
__global__ void transpose_cast_kernel(const float* __restrict__ src,
                                      unsigned short* __restrict__ dst,
                                      int R, int C) {
  __shared__ float tile[64][65];
  size_t base = (size_t)blockIdx.z * (size_t)R * (size_t)C;
  src += base; dst += base;
  int c0 = blockIdx.x * 64, r0 = blockIdx.y * 64;
  int tx = threadIdx.x, ty = threadIdx.y;  // 16 x 16
#pragma unroll
  for (int i = 0; i < 4; ++i) {
    int r = ty + i * 16;
    float4 v = *reinterpret_cast<const float4*>(src + (size_t)(r0 + r) * C + c0 + tx * 4);
    tile[r][tx * 4 + 0] = v.x;
    tile[r][tx * 4 + 1] = v.y;
    tile[r][tx * 4 + 2] = v.z;
    tile[r][tx * 4 + 3] = v.w;
  }
  __syncthreads();
#pragma unroll
  for (int j = 0; j < 4; ++j) {
    int c = ty + j * 16;
    ushort4 o;
    o.x = f2bf(tile[tx * 4 + 0][c]);
    o.y = f2bf(tile[tx * 4 + 1][c]);
    o.z = f2bf(tile[tx * 4 + 2][c]);
    o.w = f2bf(tile[tx * 4 + 3][c]);
    *reinterpret_cast<ushort4*>(dst + (size_t)(c0 + c) * R + r0 + tx * 4) = o;
  }
}

// one wave per token: f32 gate logits, top-2, renormalized weights
__global__ void gate_kernel(const float* __restrict__ x,
                            const float* __restrict__ gw,
                            int* __restrict__ topk_e,
                            float* __restrict__ topk_w,
                            int* __restrict__ counts) {
  int w = threadIdx.x >> 6, lane = threadIdx.x & 63;
  int t = blockIdx.x * 4 + w;
  const float* xr = x + (size_t)t * DIM;
  float acc[8];
#pragma unroll
  for (int e = 0; e < 8; ++e) acc[e] = 0.f;
  for (int i = 0; i < DIM / 64; ++i) {
    int d = lane + (i << 6);
    float xv = xr[d];
    float4 g0 = *reinterpret_cast<const float4*>(gw + (size_t)d * 8);
    float4 g1 = *reinterpret_cast<const float4*>(gw + (size_t)d * 8 + 4);
    acc[0] += xv * g0.x; acc[1] += xv * g0.y; acc[2] += xv * g0.z; acc[3] += xv * g0.w;
    acc[4] += xv * g1.x; acc[5] += xv * g1.y; acc[6] += xv * g1.z; acc[7] += xv * g1.w;
  }
#pragma unroll
  for (int o = 32; o; o >>= 1)
#pragma unroll
    for (int e = 0; e < 8; ++e) acc[e] += __shfl_down(acc[e], o);
  if (lane == 0) {
    int e0 = 0;
#pragma unroll
    for (int e = 1; e < 8; ++e) if (acc[e] > acc[e0]) e0 = e;
    int e1 = -1;
#pragma unroll
    for (int e = 0; e < 8; ++e) {
      if (e == e0) continue;
      if (e1 < 0 || acc[e] > acc[e1]) e1 = e;
    }
    float w0 = 1.0f / (1.0f + expf(acc[e1] - acc[e0]));  // == p0/(p0+p1)
    topk_e[t * 2 + 0] = e0;
    topk_e[t * 2 + 1] = e1;
    topk_w[t * 2 + 0] = w0;
    topk_w[t * 2 + 1] = 1.0f - w0;
    atomicAdd(&counts[e0], 1);
    atomicAdd(&counts[e1], 1);
  }
}

__global__ void offsets_kernel(const int* __restrict__ counts,
                               int* __restrict__ offsets,
                               int* __restrict__ cursor) {
  if (threadIdx.x == 0) {
    int o = 0;
    for (int e = 0; e < NEXP; ++e) {
      offsets[e] = o; cursor[e] = o; o += counts[e];
    }
    offsets[NEXP] = o;
  }
}

__global__ void scatter_kernel(const int* __restrict__ topk_e,
                               int* __restrict__ cursor,
                               int* __restrict__ rowmap,
                               int* __restrict__ inv) {
  int t = blockIdx.x * 256 + threadIdx.x;
#pragma unroll
  for (int s = 0; s < 2; ++s) {
    int e = topk_e[t * 2 + s];
    int p = atomicAdd(&cursor[e], 1);
    rowmap[p] = t * 2 + s;
    inv[t * 2 + s] = p;
  }
}

// ---------------- MFMA GEMM (128x128 tile, BK=32, m97 structure) ----------
// C[M x Ncols] = A[. x K] * Bt[Ncols x K], K-contiguous rows. 4 waves (2x2),
// per-wave 64x64 output. 32KB LDS double-buffer, gl_lds width-16 staging,
// plain __syncthreads pipeline (high occupancy: ~56 VGPR, 4-5 blocks/CU).
// Block order (MODE 0/1): expert e = bid&7 pinned to XCD e; within expert,
// (8-nt band) x mt x nt-in-band so a 32-CU window = 4 mt x 8 nt: B-band
// (2MB) stays L2-resident across the mt sweep, concurrent blocks share A.
// MODE 0: expert GEMM1, gathered A rows, epi: h = gelu(acc+b1) -> bf16
// MODE 1: expert GEMM2, compact A (h), epi: fOut[slot] = w*(acc+b2)  (f32)
// MODE 2: shared GEMM, dense, epi: fOut = 0.5*gelu(acc+b)            (f32)
template <int MODE>
__global__ __launch_bounds__(256, 4) void gemm_mfma(
    const unsigned short* __restrict__ A,
    const unsigned short* __restrict__ Ball,
    const float* __restrict__ biasAll,
    unsigned short* __restrict__ hOut,
    float* __restrict__ fOut,
    const int* __restrict__ rowmap,
    const int* __restrict__ offsets,
    const float* __restrict__ topkw,
    int K, int Ncols, int M2, int MT, int NT) {
  int bid = blockIdx.x;
  int e, mt, nt, rowBase, cnt;
  if (MODE == 2) {
    int nwg = gridDim.x;
    int lg = (bid & 7) * (nwg >> 3) + (bid >> 3);
    e = 0; rowBase = 0; cnt = M2;
    mt = lg / NT; nt = lg % NT;
  } else {
    e = bid & 7;              // expert -> XCD pinning
    int idx = bid >> 3;
    int per = MT * 8;         // one 8-nt band over all mt
    int band = idx / per;
    int r2 = idx - band * per;
    mt = r2 >> 3;
    nt = band * 8 + (r2 & 7);
    rowBase = offsets[e];
    cnt = offsets[e + 1] - rowBase;
    if (mt * 128 >= cnt) return;
  }
  const unsigned short* B = Ball + (size_t)e * Ncols * K;
  const float* bias = biasAll + (size_t)e * Ncols;

  int tid = threadIdx.x;
  int w = tid >> 6, lane = tid & 63;
  int wm = w >> 1, wn = w & 1;

  __shared__ __attribute__((aligned(16))) unsigned short As[2][128][32];
  __shared__ __attribute__((aligned(16))) unsigned short Bs[2][128][32];

  // staging: wave w covers tile rows [w*16, w*16+16) (+64 for 2nd issue);
  // lane covers row w*16 + (lane>>2), 16B chunk (lane&3) of the 64B row slice.
  int li = (w << 4) + (lane >> 2);
  int kb = (lane & 3) * 8;  // element offset

  const unsigned short* asrc[2];
#pragma unroll
  for (int rnd = 0; rnd < 2; ++rnd) {
    int i = li + rnd * 64;
    int r = mt * 128 + i;
    size_t arow;
    if (MODE == 0) {
      int rr = r < cnt ? r : cnt - 1;
      arow = (size_t)(rowmap[rowBase + rr] >> 1);
    } else if (MODE == 1) {
      int rr = r < cnt ? r : cnt - 1;
      arow = (size_t)(rowBase + rr);
    } else {
      arow = (size_t)r;
    }
    asrc[rnd] = A + arow * (size_t)K + kb;
  }
  const unsigned short* bsrc[2];
  bsrc[0] = B + (size_t)(nt * 128 + li) * K + kb;
  bsrc[1] = bsrc[0] + (size_t)64 * K;

  f32x4 acc[4][4] = {};
  int ldsrow = (w << 4);

  auto stage = [&](int buf, int kt) {
    int ko = kt * 32;
    gl_lds16(asrc[0] + ko, &As[buf][ldsrow][0]);
    gl_lds16(asrc[1] + ko, &As[buf][ldsrow + 64][0]);
    gl_lds16(bsrc[0] + ko, &Bs[buf][ldsrow][0]);
    gl_lds16(bsrc[1] + ko, &Bs[buf][ldsrow + 64][0]);
  };

  stage(0, 0);
  __syncthreads();

  int KT = K >> 5;
  int fr = lane & 15, fg = lane >> 4;
  for (int kt = 0; kt < KT; ++kt) {
    int cur = kt & 1;
    if (kt + 1 < KT) stage(cur ^ 1, kt + 1);
    s16x8 af[4], bf[4];
#pragma unroll
    for (int m = 0; m < 4; ++m)
      af[m] = *reinterpret_cast<const s16x8*>(&As[cur][wm * 64 + m * 16 + fr][fg * 8]);
#pragma unroll
    for (int n = 0; n < 4; ++n)
      bf[n] = *reinterpret_cast<const s16x8*>(&Bs[cur][wn * 64 + n * 16 + fr][fg * 8]);
#pragma unroll
    for (int m = 0; m < 4; ++m)
#pragma unroll
      for (int n = 0; n < 4; ++n)
        acc[m][n] = __builtin_amdgcn_mfma_f32_16x16x32_bf16(
            __builtin_bit_cast(b16x8, af[m]), __builtin_bit_cast(b16x8, bf[n]),
            acc[m][n], 0, 0, 0);
    __syncthreads();
  }

  // epilogue: C/D layout col=lane&15, row=(lane>>4)*4+q
#pragma unroll
  for (int m = 0; m < 4; ++m) {
#pragma unroll
    for (int q = 0; q < 4; ++q) {
      int rloc = wm * 64 + m * 16 + fg * 4 + q;
      int r = mt * 128 + rloc;
      if (MODE != 2 && r >= cnt) continue;
      if (MODE == 0) {
        size_t orow = (size_t)(rowBase + r) * Ncols;
#pragma unroll
        for (int n = 0; n < 4; ++n) {
          int col = nt * 128 + wn * 64 + n * 16 + fr;
          float v = acc[m][n][q] + bias[col];
          hOut[orow + col] = f2bf(gelu_f(v));
        }
      } else if (MODE == 1) {
        float wgt = topkw[rowmap[rowBase + r]];
        float* orow = fOut + (size_t)(rowBase + r) * Ncols;
#pragma unroll
        for (int n = 0; n < 4; ++n) {
          int col = nt * 128 + wn * 64 + n * 16 + fr;
          orow[col] = wgt * (acc[m][n][q] + bias[col]);
        }
      } else {
        float* orow = fOut + (size_t)r * Ncols;
#pragma unroll
        for (int n = 0; n < 4; ++n) {
          int col = nt * 128 + wn * 64 + n * 16 + fr;
          orow[col] = 0.5f * gelu_f(acc[m][n][q] + bias[col]);
        }
      }
    }
  }
}

// ---------------- LayerNorm (gathers shared + 2 expert slots) ----------------
__global__ void ln_kernel(const float* __restrict__ sh,
                          const float* __restrict__ acc2,
                          const int* __restrict__ inv,
                          const float* __restrict__ gamma,
                          const float* __restrict__ beta,
                          float* __restrict__ out) {
  int t = blockIdx.x, tid = threadIdx.x;
  int i0 = inv[t * 2 + 0], i1 = inv[t * 2 + 1];
  float4 a  = reinterpret_cast<const float4*>(sh   + (size_t)t  * DOUT)[tid];
  float4 c0 = reinterpret_cast<const float4*>(acc2 + (size_t)i0 * DOUT)[tid];
  float4 c1 = reinterpret_cast<const float4*>(acc2 + (size_t)i1 * DOUT)[tid];
  float4 v;
  v.x = a.x + c0.x + c1.x;
  v.y = a.y + c0.y + c1.y;
  v.z = a.z + c0.z + c1.z;
  v.w = a.w + c0.w + c1.w;
  float s = v.x + v.y + v.z + v.w;
  float q = v.x * v.x + v.y * v.y + v.z * v.z + v.w * v.w;
#pragma unroll
  for (int o = 32; o; o >>= 1) {
    s += __shfl_down(s, o);
    q += __shfl_down(q, o);
  }
  __shared__ float ss[4], sq[4];
  int w = tid >> 6, lane = tid & 63;
  if (lane == 0) { ss[w] = s; sq[w] = q; }
  __syncthreads();
  float S = ss[0] + ss[1] + ss[2] + ss[3];
  float Q = sq[0] + sq[1] + sq[2] + sq[3];
  float mean = S * (1.0f / DOUT);
  float var = Q * (1.0f / DOUT) - mean * mean;
  float inv_std = rsqrtf(var + 1e-5f);
  float4 g = reinterpret_cast<const float4*>(gamma)[tid];
  float4 b = reinterpret_cast<const float4*>(beta)[tid];
  float4 o;
  o.x = (v.x - mean) * inv_std * g.x + b.x;
  o.y = (v.y - mean) * inv_std * g.y + b.y;
  o.z = (v.z - mean) * inv_std * g.z + b.z;
  o.w = (v.w - mean) * inv_std * g.w + b.w;
  reinterpret_cast<float4*>(out + (size_t)t * DOUT)[tid] = o;
}

// ---------------- host ----------------
extern "C" void kernel_launch(void* const* d_in, const int* in_sizes, int n_in,
                              void* d_out, int out_size, void* d_ws, size_t ws_size,
                              hipStream_t stream) {
  const float* x       = (const float*)d_in[0];
  const float* W1      = (const float*)d_in[1];
  const float* b1      = (const float*)d_in[2];
  const float* W2      = (const float*)d_in[3];
  const float* b2      = (const float*)d_in[4];
  const float* gateW   = (const float*)d_in[5];
  const float* sharedW = (const float*)d_in[6];
  const float* sharedB = (const float*)d_in[7];
  const float* gamma   = (const float*)d_in[8];
  const float* beta    = (const float*)d_in[9];
  float* out = (float*)d_out;

  char* ws = (char*)d_ws;
  size_t off = 0;
  auto alloc = [&](size_t bytes) -> void* {
    void* p = ws + off;
    off += (bytes + 255) & ~(size_t)255;
    return p;
  };
  int*   counts = (int*)alloc(NEXP * 4);
  int*   offs   = (int*)alloc((NEXP + 1) * 4);
  int*   cursor = (int*)alloc(NEXP * 4);
  int*   topk_e = (int*)alloc((size_t)N_TOK * 2 * 4);
  float* topk_w = (float*)alloc((size_t)N_TOK * 2 * 4);
  int*   rowmap = (int*)alloc((size_t)N_TOK * 2 * 4);
  int*   inv    = (int*)alloc((size_t)N_TOK * 2 * 4);
  unsigned short* xbf  = (unsigned short*)alloc((size_t)N_TOK * DIM * 2);
  unsigned short* W1t  = (unsigned short*)alloc((size_t)NEXP * HID * DIM * 2);
  unsigned short* W2t  = (unsigned short*)alloc((size_t)NEXP * DOUT * HID * 2);
  unsigned short* sWt  = (unsigned short*)alloc((size_t)DOUT * DIM * 2);
  unsigned short* hbuf = (unsigned short*)alloc((size_t)N_TOK * 2 * HID * 2);
  float* acc2 = (float*)alloc((size_t)N_TOK * 2 * DOUT * 4);
  // shbuf aliases W1t (W1t dead after GEMM1; shared GEMM launches after it)
  float* shbuf = (float*)W1t;
  if (off > ws_size) return;  // workspace too small -> fail validation loudly

  init_kernel<<<1, 64, 0, stream>>>(counts);
  cast_x_kernel<<<N_TOK * DIM / 1024, 256, 0, stream>>>(x, xbf);
  transpose_cast_kernel<<<dim3(HID / 64, DIM / 64, NEXP), dim3(16, 16), 0, stream>>>(W1, W1t, DIM, HID);
  transpose_cast_kernel<<<dim3(DOUT / 64, HID / 64, NEXP), dim3(16, 16), 0, stream>>>(W2, W2t, HID, DOUT);
  transpose_cast_kernel<<<dim3(DOUT / 64, DIM / 64, 1), dim3(16, 16), 0, stream>>>(sharedW, sWt, DIM, DOUT);
  gate_kernel<<<N_TOK / 4, 256, 0, stream>>>(x, gateW, topk_e, topk_w, counts);
  offsets_kernel<<<1, 64, 0, stream>>>(counts, offs, cursor);
  scatter_kernel<<<N_TOK / 256, 256, 0, stream>>>(topk_e, cursor, rowmap, inv);

  // GEMM1: h = gelu(x @ W1 + b1). MT=64 (covers any routing skew), NT=32.
  gemm_mfma<0><<<NEXP * 64 * (HID / 128), 256, 0, stream>>>(
      xbf, W1t, b1, hbuf, nullptr, rowmap, offs, topk_w, DIM, HID, 0, 64, HID / 128);
  // shared: shbuf = 0.5*gelu(x @ sharedW + sb)
  gemm_mfma<2><<<(N_TOK / 128) * (DOUT / 128), 256, 0, stream>>>(
      xbf, sWt, sharedB, nullptr, shbuf, nullptr, nullptr, nullptr, DIM, DOUT,
      N_TOK, N_TOK / 128, DOUT / 128);
  // GEMM2: acc2[slot] = w * (h @ W2 + b2)   (compact, no atomics)
  gemm_mfma<1><<<NEXP * 64 * (DOUT / 128), 256, 0, stream>>>(
      hbuf, W2t, b2, nullptr, acc2, rowmap, offs, topk_w, HID, DOUT, 0, 64, DOUT / 128);
  // LayerNorm(shared + slot0 + slot1) -> out
  ln_kernel<<<N_TOK, 256, 0, stream>>>(shbuf, acc2, inv, gamma, beta, out);
}

// Round 5
// 809.389 us; speedup vs baseline: 1.3427x; 1.0446x over previous
//
#include <hip/hip_runtime.h>
#include <cstdint>
#include <cstddef>

#define N_TOK 8192
#define DIM   1024
#define HID   4096
#define DOUT  1024
#define NEXP  8

typedef short  s16x8 __attribute__((ext_vector_type(8)));
typedef __bf16 b16x8 __attribute__((ext_vector_type(8)));
typedef float  f32x4 __attribute__((ext_vector_type(4)));

__device__ __forceinline__ unsigned short f2bf(float f) {
  unsigned u = __float_as_uint(f);
  u += 0x7fffu + ((u >> 16) & 1u);
  return (unsigned short)(u >> 16);
}

// tanh-form GELU via one fast exp: max |err| vs exact erf-GELU ~3e-4,
// 25x below bf16 quantization of h. ~8 VALU ops vs ~25-30 for erff.
__device__ __forceinline__ float gelu_fast(float v) {
  float u2 = v * (1.5957691216f + 0.0713548163f * v * v);  // 2*sqrt(2/pi)*(v+c*v^3)
  return v / (1.0f + __expf(-u2));
}

// async global->LDS, 16B per lane. LDS dest wave-uniform base; HW writes
// lane i at base + i*16. Global src is per-lane.
__device__ __forceinline__ void gl_lds16(const void* g, void* l) {
  auto gp = (__attribute__((address_space(1))) void*)(reinterpret_cast<uintptr_t>(g));
  auto lp = (__attribute__((address_space(3))) void*)(reinterpret_cast<uintptr_t>(l));
  __builtin_amdgcn_global_load_lds(gp, lp, 16, 0, 0);
}

// ---------------- small kernels ----------------

__global__ void init_kernel(int* counts) {
  if (threadIdx.x < NEXP) counts[threadIdx.x] = 0;
}

__global__ void cast_x_kernel(const float* __restrict__ src,
                              unsigned short* __restrict__ dst) {
  int i = blockIdx.x * 256 + threadIdx.x;
  float4 v = reinterpret_cast<const float4*>(src)[i];
  ushort4 o;
  o.x = f2bf(v.x); o.y = f2bf(v.y); o.z = f2bf(v.z); o.w = f2bf(v.w);
  reinterpret_cast<ushort4*>(dst)[i] = o;
}

// src [R][C] f32 (batched by blockIdx.z) -> dst [C][R] bf16.
// 64x64 tile; float4 reads, ushort4 writes (full 128B lines per dst row).
__global__ void transpose_cast_kernel(const float* __restrict__ src,
                                      unsigned short* __restrict__ dst,
                                      int R, int C) {
  __shared__ float tile[64][65];
  size_t base = (size_t)blockIdx.z * (size_t)R * (size_t)C;
  src += base; dst += base;
  int c0 = blockIdx.x * 64, r0 = blockIdx.y * 64;
  int tx = threadIdx.x, ty = threadIdx.y;  // 16 x 16
#pragma unroll
  for (int i = 0; i < 4; ++i) {
    int r = ty + i * 16;
    float4 v = *reinterpret_cast<const float4*>(src + (size_t)(r0 + r) * C + c0 + tx * 4);
    tile[r][tx * 4 + 0] = v.x;
    tile[r][tx * 4 + 1] = v.y;
    tile[r][tx * 4 + 2] = v.z;
    tile[r][tx * 4 + 3] = v.w;
  }
  __syncthreads();
#pragma unroll
  for (int j = 0; j < 4; ++j) {
    int c = ty + j * 16;
    ushort4 o;
    o.x = f2bf(tile[tx * 4 + 0][c]);
    o.y = f2bf(tile[tx * 4 + 1][c]);
    o.z = f2bf(tile[tx * 4 + 2][c]);
    o.w = f2bf(tile[tx * 4 + 3][c]);
    *reinterpret_cast<ushort4*>(dst + (size_t)(c0 + c) * R + r0 + tx * 4) = o;
  }
}

// one wave per token: f32 gate logits, top-2, renormalized weights
__global__ void gate_kernel(const float* __restrict__ x,
                            const float* __restrict__ gw,
                            int* __restrict__ topk_e,
                            float* __restrict__ topk_w,
                            int* __restrict__ counts) {
  int w = threadIdx.x >> 6, lane = threadIdx.x & 63;
  int t = blockIdx.x * 4 + w;
  const float* xr = x + (size_t)t * DIM;
  float acc[8];
#pragma unroll
  for (int e = 0; e < 8; ++e) acc[e] = 0.f;
  for (int i = 0; i < DIM / 64; ++i) {
    int d = lane + (i << 6);
    float xv = xr[d];
    float4 g0 = *reinterpret_cast<const float4*>(gw + (size_t)d * 8);
    float4 g1 = *reinterpret_cast<const float4*>(gw + (size_t)d * 8 + 4);
    acc[0] += xv * g0.x; acc[1] += xv * g0.y; acc[2] += xv * g0.z; acc[3] += xv * g0.w;
    acc[4] += xv * g1.x; acc[5] += xv * g1.y; acc[6] += xv * g1.z; acc[7] += xv * g1.w;
  }
#pragma unroll
  for (int o = 32; o; o >>= 1)
#pragma unroll
    for (int e = 0; e < 8; ++e) acc[e] += __shfl_down(acc[e], o);
  if (lane == 0) {
    int e0 = 0;
#pragma unroll
    for (int e = 1; e < 8; ++e) if (acc[e] > acc[e0]) e0 = e;
    int e1 = -1;
#pragma unroll
    for (int e = 0; e < 8; ++e) {
      if (e == e0) continue;
      if (e1 < 0 || acc[e] > acc[e1]) e1 = e;
    }
    float w0 = 1.0f / (1.0f + expf(acc[e1] - acc[e0]));  // == p0/(p0+p1)
    topk_e[t * 2 + 0] = e0;
    topk_e[t * 2 + 1] = e1;
    topk_w[t * 2 + 0] = w0;
    topk_w[t * 2 + 1] = 1.0f - w0;
    atomicAdd(&counts[e0], 1);
    atomicAdd(&counts[e1], 1);
  }
}

__global__ void offsets_kernel(const int* __restrict__ counts,
                               int* __restrict__ offsets,
                               int* __restrict__ cursor) {
  if (threadIdx.x == 0) {
    int o = 0;
    for (int e = 0; e < NEXP; ++e) {
      offsets[e] = o; cursor[e] = o; o += counts[e];
    }
    offsets[NEXP] = o;
  }
}

__global__ void scatter_kernel(const int* __restrict__ topk_e,
                               int* __restrict__ cursor,
                               int* __restrict__ rowmap,
                               int* __restrict__ inv) {
  int t = blockIdx.x * 256 + threadIdx.x;
#pragma unroll
  for (int s = 0; s < 2; ++s) {
    int e = topk_e[t * 2 + s];
    int p = atomicAdd(&cursor[e], 1);
    rowmap[p] = t * 2 + s;
    inv[t * 2 + s] = p;
  }
}

// ---------------- MFMA GEMM (128x128 tile, BK=32, m97 structure) ----------
// C[M x Ncols] = A[. x K] * Bt[Ncols x K], K-contiguous rows. 4 waves (2x2),
// per-wave 64x64 output. 32KB LDS double-buffer, gl_lds width-16 staging,
// plain __syncthreads pipeline (high occupancy: ~56 VGPR, 4 blocks/CU).
// Block order (MODE 0/1): expert e = bid&7 pinned to XCD e; within expert,
// (8-nt band) x mt x nt-in-band so a 32-CU window = 4 mt x 8 nt: B-band
// (2MB) stays L2-resident across the mt sweep, concurrent blocks share A.
// MODE 0: expert GEMM1, gathered A rows, epi: h = gelu(acc+b1) -> bf16
// MODE 1: expert GEMM2, compact A (h), epi: fOut[slot] = w*(acc+b2)  (f32)
// MODE 2: shared GEMM, dense, epi: fOut = 0.5*gelu(acc+b)            (f32)
template <int MODE>
__global__ __launch_bounds__(256, 4) void gemm_mfma(
    const unsigned short* __restrict__ A,
    const unsigned short* __restrict__ Ball,
    const float* __restrict__ biasAll,
    unsigned short* __restrict__ hOut,
    float* __restrict__ fOut,
    const int* __restrict__ rowmap,
    const int* __restrict__ offsets,
    const float* __restrict__ topkw,
    int K, int Ncols, int M2, int MT, int NT) {
  int bid = blockIdx.x;
  int e, mt, nt, rowBase, cnt;
  if (MODE == 2) {
    int nwg = gridDim.x;
    int lg = (bid & 7) * (nwg >> 3) + (bid >> 3);
    e = 0; rowBase = 0; cnt = M2;
    mt = lg / NT; nt = lg % NT;
  } else {
    e = bid & 7;              // expert -> XCD pinning
    int idx = bid >> 3;
    int per = MT * 8;         // one 8-nt band over all mt
    int band = idx / per;
    int r2 = idx - band * per;
    mt = r2 >> 3;
    nt = band * 8 + (r2 & 7);
    rowBase = offsets[e];
    cnt = offsets[e + 1] - rowBase;
    if (mt * 128 >= cnt) return;
  }
  const unsigned short* B = Ball + (size_t)e * Ncols * K;
  const float* bias = biasAll + (size_t)e * Ncols;

  int tid = threadIdx.x;
  int w = tid >> 6, lane = tid & 63;
  int wm = w >> 1, wn = w & 1;

  __shared__ __attribute__((aligned(16))) unsigned short As[2][128][32];
  __shared__ __attribute__((aligned(16))) unsigned short Bs[2][128][32];

  // staging: wave w covers tile rows [w*16, w*16+16) (+64 for 2nd issue);
  // lane covers row w*16 + (lane>>2), 16B chunk (lane&3) of the 64B row slice.
  int li = (w << 4) + (lane >> 2);
  int kb = (lane & 3) * 8;  // element offset

  const unsigned short* asrc[2];
#pragma unroll
  for (int rnd = 0; rnd < 2; ++rnd) {
    int i = li + rnd * 64;
    int r = mt * 128 + i;
    size_t arow;
    if (MODE == 0) {
      int rr = r < cnt ? r : cnt - 1;
      arow = (size_t)(rowmap[rowBase + rr] >> 1);
    } else if (MODE == 1) {
      int rr = r < cnt ? r : cnt - 1;
      arow = (size_t)(rowBase + rr);
    } else {
      arow = (size_t)r;
    }
    asrc[rnd] = A + arow * (size_t)K + kb;
  }
  const unsigned short* bsrc[2];
  bsrc[0] = B + (size_t)(nt * 128 + li) * K + kb;
  bsrc[1] = bsrc[0] + (size_t)64 * K;

  f32x4 acc[4][4] = {};
  int ldsrow = (w << 4);

  auto stage = [&](int buf, int kt) {
    int ko = kt * 32;
    gl_lds16(asrc[0] + ko, &As[buf][ldsrow][0]);
    gl_lds16(asrc[1] + ko, &As[buf][ldsrow + 64][0]);
    gl_lds16(bsrc[0] + ko, &Bs[buf][ldsrow][0]);
    gl_lds16(bsrc[1] + ko, &Bs[buf][ldsrow + 64][0]);
  };

  stage(0, 0);
  __syncthreads();

  int KT = K >> 5;
  int fr = lane & 15, fg = lane >> 4;
  for (int kt = 0; kt < KT; ++kt) {
    int cur = kt & 1;
    if (kt + 1 < KT) stage(cur ^ 1, kt + 1);
    s16x8 af[4], bf[4];
#pragma unroll
    for (int m = 0; m < 4; ++m)
      af[m] = *reinterpret_cast<const s16x8*>(&As[cur][wm * 64 + m * 16 + fr][fg * 8]);
#pragma unroll
    for (int n = 0; n < 4; ++n)
      bf[n] = *reinterpret_cast<const s16x8*>(&Bs[cur][wn * 64 + n * 16 + fr][fg * 8]);
#pragma unroll
    for (int m = 0; m < 4; ++m)
#pragma unroll
      for (int n = 0; n < 4; ++n)
        acc[m][n] = __builtin_amdgcn_mfma_f32_16x16x32_bf16(
            __builtin_bit_cast(b16x8, af[m]), __builtin_bit_cast(b16x8, bf[n]),
            acc[m][n], 0, 0, 0);
    __syncthreads();
  }

  // epilogue: C/D layout col=lane&15, row=(lane>>4)*4+q
#pragma unroll
  for (int m = 0; m < 4; ++m) {
#pragma unroll
    for (int q = 0; q < 4; ++q) {
      int rloc = wm * 64 + m * 16 + fg * 4 + q;
      int r = mt * 128 + rloc;
      if (MODE != 2 && r >= cnt) continue;
      if (MODE == 0) {
        size_t orow = (size_t)(rowBase + r) * Ncols;
#pragma unroll
        for (int n = 0; n < 4; ++n) {
          int col = nt * 128 + wn * 64 + n * 16 + fr;
          float v = acc[m][n][q] + bias[col];
          hOut[orow + col] = f2bf(gelu_fast(v));
        }
      } else if (MODE == 1) {
        float wgt = topkw[rowmap[rowBase + r]];
        float* orow = fOut + (size_t)(rowBase + r) * Ncols;
#pragma unroll
        for (int n = 0; n < 4; ++n) {
          int col = nt * 128 + wn * 64 + n * 16 + fr;
          orow[col] = wgt * (acc[m][n][q] + bias[col]);
        }
      } else {
        float* orow = fOut + (size_t)r * Ncols;
#pragma unroll
        for (int n = 0; n < 4; ++n) {
          int col = nt * 128 + wn * 64 + n * 16 + fr;
          orow[col] = 0.5f * gelu_fast(acc[m][n][q] + bias[col]);
        }
      }
    }
  }
}

// ---------------- LayerNorm (gathers shared + 2 expert slots) ----------------
__global__ void ln_kernel(const float* __restrict__ sh,
                          const float* __restrict__ acc2,
                          const int* __restrict__ inv,
                          const float* __restrict__ gamma,
                          const float* __restrict__ beta,
                          float* __restrict__ out) {
  int t = blockIdx.x, tid = threadIdx.x;
  int i0 = inv[t * 2 + 0], i1 = inv[t * 2 + 1];
  float4 a  = reinterpret_cast<const float4*>(sh   + (size_t)t  * DOUT)[tid];
  float4 c0 = reinterpret_cast<const float4*>(acc2 + (size_t)i0 * DOUT)[tid];
  float4 c1 = reinterpret_cast<const float4*>(acc2 + (size_t)i1 * DOUT)[tid];
  float4 v;
  v.x = a.x + c0.x + c1.x;
  v.y = a.y + c0.y + c1.y;
  v.z = a.z + c0.z + c1.z;
  v.w = a.w + c0.w + c1.w;
  float s = v.x + v.y + v.z + v.w;
  float q = v.x * v.x + v.y * v.y + v.z * v.z + v.w * v.w;
#pragma unroll
  for (int o = 32; o; o >>= 1) {
    s += __shfl_down(s, o);
    q += __shfl_down(q, o);
  }
  __shared__ float ss[4], sq[4];
  int w = tid >> 6, lane = tid & 63;
  if (lane == 0) { ss[w] = s; sq[w] = q; }
  __syncthreads();
  float S = ss[0] + ss[1] + ss[2] + ss[3];
  float Q = sq[0] + sq[1] + sq[2] + sq[3];
  float mean = S * (1.0f / DOUT);
  float var = Q * (1.0f / DOUT) - mean * mean;
  float inv_std = rsqrtf(var + 1e-5f);
  float4 g = reinterpret_cast<const float4*>(gamma)[tid];
  float4 b = reinterpret_cast<const float4*>(beta)[tid];
  float4 o;
  o.x = (v.x - mean) * inv_std * g.x + b.x;
  o.y = (v.y - mean) * inv_std * g.y + b.y;
  o.z = (v.z - mean) * inv_std * g.z + b.z;
  o.w = (v.w - mean) * inv_std * g.w + b.w;
  reinterpret_cast<float4*>(out + (size_t)t * DOUT)[tid] = o;
}

// ---------------- host ----------------
extern "C" void kernel_launch(void* const* d_in, const int* in_sizes, int n_in,
                              void* d_out, int out_size, void* d_ws, size_t ws_size,
                              hipStream_t stream) {
  const float* x       = (const float*)d_in[0];
  const float* W1      = (const float*)d_in[1];
  const float* b1      = (const float*)d_in[2];
  const float* W2      = (const float*)d_in[3];
  const float* b2      = (const float*)d_in[4];
  const float* gateW   = (const float*)d_in[5];
  const float* sharedW = (const float*)d_in[6];
  const float* sharedB = (const float*)d_in[7];
  const float* gamma   = (const float*)d_in[8];
  const float* beta    = (const float*)d_in[9];
  float* out = (float*)d_out;

  char* ws = (char*)d_ws;
  size_t off = 0;
  auto alloc = [&](size_t bytes) -> void* {
    void* p = ws + off;
    off += (bytes + 255) & ~(size_t)255;
    return p;
  };
  int*   counts = (int*)alloc(NEXP * 4);
  int*   offs   = (int*)alloc((NEXP + 1) * 4);
  int*   cursor = (int*)alloc(NEXP * 4);
  int*   topk_e = (int*)alloc((size_t)N_TOK * 2 * 4);
  float* topk_w = (float*)alloc((size_t)N_TOK * 2 * 4);
  int*   rowmap = (int*)alloc((size_t)N_TOK * 2 * 4);
  int*   inv    = (int*)alloc((size_t)N_TOK * 2 * 4);
  unsigned short* xbf  = (unsigned short*)alloc((size_t)N_TOK * DIM * 2);
  unsigned short* W1t  = (unsigned short*)alloc((size_t)NEXP * HID * DIM * 2);
  unsigned short* W2t  = (unsigned short*)alloc((size_t)NEXP * DOUT * HID * 2);
  unsigned short* sWt  = (unsigned short*)alloc((size_t)DOUT * DIM * 2);
  unsigned short* hbuf = (unsigned short*)alloc((size_t)N_TOK * 2 * HID * 2);
  float* acc2 = (float*)alloc((size_t)N_TOK * 2 * DOUT * 4);
  // shbuf aliases W1t (W1t dead after GEMM1; shared GEMM launches after it)
  float* shbuf = (float*)W1t;
  if (off > ws_size) return;  // workspace too small -> fail validation loudly

  init_kernel<<<1, 64, 0, stream>>>(counts);
  cast_x_kernel<<<N_TOK * DIM / 1024, 256, 0, stream>>>(x, xbf);
  transpose_cast_kernel<<<dim3(HID / 64, DIM / 64, NEXP), dim3(16, 16), 0, stream>>>(W1, W1t, DIM, HID);
  transpose_cast_kernel<<<dim3(DOUT / 64, HID / 64, NEXP), dim3(16, 16), 0, stream>>>(W2, W2t, HID, DOUT);
  transpose_cast_kernel<<<dim3(DOUT / 64, DIM / 64, 1), dim3(16, 16), 0, stream>>>(sharedW, sWt, DIM, DOUT);
  gate_kernel<<<N_TOK / 4, 256, 0, stream>>>(x, gateW, topk_e, topk_w, counts);
  offsets_kernel<<<1, 64, 0, stream>>>(counts, offs, cursor);
  scatter_kernel<<<N_TOK / 256, 256, 0, stream>>>(topk_e, cursor, rowmap, inv);

  // GEMM1: h = gelu(x @ W1 + b1). MT=32 (cnt>4096 is a >20-sigma event;
  // clamp+early-exit still guard), NT=32.
  gemm_mfma<0><<<NEXP * 32 * (HID / 128), 256, 0, stream>>>(
      xbf, W1t, b1, hbuf, nullptr, rowmap, offs, topk_w, DIM, HID, 0, 32, HID / 128);
  // shared: shbuf = 0.5*gelu(x @ sharedW + sb)
  gemm_mfma<2><<<(N_TOK / 128) * (DOUT / 128), 256, 0, stream>>>(
      xbf, sWt, sharedB, nullptr, shbuf, nullptr, nullptr, nullptr, DIM, DOUT,
      N_TOK, N_TOK / 128, DOUT / 128);
  // GEMM2: acc2[slot] = w * (h @ W2 + b2)   (compact, no atomics)
  gemm_mfma<1><<<NEXP * 32 * (DOUT / 128), 256, 0, stream>>>(
      hbuf, W2t, b2, nullptr, acc2, rowmap, offs, topk_w, HID, DOUT, 0, 32, DOUT / 128);
  // LayerNorm(shared + slot0 + slot1) -> out
  ln_kernel<<<N_TOK, 256, 0, stream>>>(shbuf, acc2, inv, gamma, beta, out);
}

// Round 6
// 780.323 us; speedup vs baseline: 1.3927x; 1.0372x over previous
//
#include <hip/hip_runtime.h>
#include <cstdint>
#include <cstddef>

#define N_TOK 8192
#define DIM   1024
#define HID   4096
#define DOUT  1024
#define NEXP  8

typedef short  s16x8 __attribute__((ext_vector_type(8)));
typedef __bf16 b16x8 __attribute__((ext_vector_type(8)));
typedef float  f32x4 __attribute__((ext_vector_type(4)));

__device__ __forceinline__ unsigned short f2bf(float f) {
  unsigned u = __float_as_uint(f);
  u += 0x7fffu + ((u >> 16) & 1u);
  return (unsigned short)(u >> 16);
}

__device__ __forceinline__ float bf2f(unsigned short u) {
  return __uint_as_float((unsigned)u << 16);
}

// tanh-form GELU via one fast exp: max |err| vs exact erf-GELU ~3e-4,
// 25x below bf16 quantization of h. ~8 VALU ops vs ~25-30 for erff.
__device__ __forceinline__ float gelu_fast(float v) {
  float u2 = v * (1.5957691216f + 0.0713548163f * v * v);  // 2*sqrt(2/pi)*(v+c*v^3)
  return v / (1.0f + __expf(-u2));
}

// async global->LDS, 16B per lane. LDS dest wave-uniform base; HW writes
// lane i at base + i*16. Global src is per-lane.
__device__ __forceinline__ void gl_lds16(const void* g, void* l) {
  auto gp = (__attribute__((address_space(1))) void*)(reinterpret_cast<uintptr_t>(g));
  auto lp = (__attribute__((address_space(3))) void*)(reinterpret_cast<uintptr_t>(l));
  __builtin_amdgcn_global_load_lds(gp, lp, 16, 0, 0);
}

// ---------------- small kernels ----------------

__global__ void init_kernel(int* counts) {
  if (threadIdx.x < NEXP) counts[threadIdx.x] = 0;
}

__global__ void cast_x_kernel(const float* __restrict__ src,
                              unsigned short* __restrict__ dst) {
  int i = blockIdx.x * 256 + threadIdx.x;
  float4 v = reinterpret_cast<const float4*>(src)[i];
  ushort4 o;
  o.x = f2bf(v.x); o.y = f2bf(v.y); o.z = f2bf(v.z); o.w = f2bf(v.w);
  reinterpret_cast<ushort4*>(dst)[i] = o;
}

// src [R][C] f32 (batched by blockIdx.z) -> dst [C][R] bf16.
// 64x64 tile; float4 reads, ushort4 writes (full 128B lines per dst row).
__global__ void transpose_cast_kernel(const float* __restrict__ src,
                                      unsigned short* __restrict__ dst,
                                      int R, int C) {
  __shared__ float tile[64][65];
  size_t base = (size_t)blockIdx.z * (size_t)R * (size_t)C;
  src += base; dst += base;
  int c0 = blockIdx.x * 64, r0 = blockIdx.y * 64;
  int tx = threadIdx.x, ty = threadIdx.y;  // 16 x 16
#pragma unroll
  for (int i = 0; i < 4; ++i) {
    int r = ty + i * 16;
    float4 v = *reinterpret_cast<const float4*>(src + (size_t)(r0 + r) * C + c0 + tx * 4);
    tile[r][tx * 4 + 0] = v.x;
    tile[r][tx * 4 + 1] = v.y;
    tile[r][tx * 4 + 2] = v.z;
    tile[r][tx * 4 + 3] = v.w;
  }
  __syncthreads();
#pragma unroll
  for (int j = 0; j < 4; ++j) {
    int c = ty + j * 16;
    ushort4 o;
    o.x = f2bf(tile[tx * 4 + 0][c]);
    o.y = f2bf(tile[tx * 4 + 1][c]);
    o.z = f2bf(tile[tx * 4 + 2][c]);
    o.w = f2bf(tile[tx * 4 + 3][c]);
    *reinterpret_cast<ushort4*>(dst + (size_t)(c0 + c) * R + r0 + tx * 4) = o;
  }
}

// one wave per token: f32 gate logits, top-2, renormalized weights
__global__ void gate_kernel(const float* __restrict__ x,
                            const float* __restrict__ gw,
                            int* __restrict__ topk_e,
                            float* __restrict__ topk_w,
                            int* __restrict__ counts) {
  int w = threadIdx.x >> 6, lane = threadIdx.x & 63;
  int t = blockIdx.x * 4 + w;
  const float* xr = x + (size_t)t * DIM;
  float acc[8];
#pragma unroll
  for (int e = 0; e < 8; ++e) acc[e] = 0.f;
  for (int i = 0; i < DIM / 64; ++i) {
    int d = lane + (i << 6);
    float xv = xr[d];
    float4 g0 = *reinterpret_cast<const float4*>(gw + (size_t)d * 8);
    float4 g1 = *reinterpret_cast<const float4*>(gw + (size_t)d * 8 + 4);
    acc[0] += xv * g0.x; acc[1] += xv * g0.y; acc[2] += xv * g0.z; acc[3] += xv * g0.w;
    acc[4] += xv * g1.x; acc[5] += xv * g1.y; acc[6] += xv * g1.z; acc[7] += xv * g1.w;
  }
#pragma unroll
  for (int o = 32; o; o >>= 1)
#pragma unroll
    for (int e = 0; e < 8; ++e) acc[e] += __shfl_down(acc[e], o);
  if (lane == 0) {
    int e0 = 0;
#pragma unroll
    for (int e = 1; e < 8; ++e) if (acc[e] > acc[e0]) e0 = e;
    int e1 = -1;
#pragma unroll
    for (int e = 0; e < 8; ++e) {
      if (e == e0) continue;
      if (e1 < 0 || acc[e] > acc[e1]) e1 = e;
    }
    float w0 = 1.0f / (1.0f + expf(acc[e1] - acc[e0]));  // == p0/(p0+p1)
    topk_e[t * 2 + 0] = e0;
    topk_e[t * 2 + 1] = e1;
    topk_w[t * 2 + 0] = w0;
    topk_w[t * 2 + 1] = 1.0f - w0;
    atomicAdd(&counts[e0], 1);
    atomicAdd(&counts[e1], 1);
  }
}

__global__ void offsets_kernel(const int* __restrict__ counts,
                               int* __restrict__ offsets,
                               int* __restrict__ cursor) {
  if (threadIdx.x == 0) {
    int o = 0;
    for (int e = 0; e < NEXP; ++e) {
      offsets[e] = o; cursor[e] = o; o += counts[e];
    }
    offsets[NEXP] = o;
  }
}

__global__ void scatter_kernel(const int* __restrict__ topk_e,
                               int* __restrict__ cursor,
                               int* __restrict__ rowmap,
                               int* __restrict__ inv) {
  int t = blockIdx.x * 256 + threadIdx.x;
#pragma unroll
  for (int s = 0; s < 2; ++s) {
    int e = topk_e[t * 2 + s];
    int p = atomicAdd(&cursor[e], 1);
    rowmap[p] = t * 2 + s;
    inv[t * 2 + s] = p;
  }
}

// ---------------- MFMA GEMM (128x128 tile, BK=32, 3-buffer ring) ----------
// C[M x Ncols] = A[. x K] * Bt[Ncols x K], K-contiguous rows. 4 waves (2x2),
// per-wave 64x64 output. 48KB LDS (3-buffer ring, 3 blocks/CU), gl_lds
// width-16 staging 2 K-tiles AHEAD, counted s_waitcnt vmcnt(4) (never 0 in
// the loop) + one raw s_barrier per K-step: staging latency (LLC-class,
// since a whole expert's tiles are co-resident per XCD) stays hidden.
// Ring safety: buf[(kt+2)%3] was last read at iter kt-1; lgkmcnt(0) before
// iter kt-1's barrier drains those reads before the overwrite can land.
// Block order (MODE 0/1): expert e = bid&7 pinned to XCD e; within expert,
// (8-nt band) x mt x nt-in-band for B-band L2 residency.
// MODE 0: expert GEMM1, gathered A rows, epi: h = gelu(acc+b1) -> bf16
// MODE 1: expert GEMM2, compact A (h), epi: out[slot] = w*(acc+b2) -> bf16
// MODE 2: shared GEMM, dense, epi: out = 0.5*gelu(acc+b) -> bf16
template <int MODE>
__global__ __launch_bounds__(256, 3) void gemm_mfma(
    const unsigned short* __restrict__ A,
    const unsigned short* __restrict__ Ball,
    const float* __restrict__ biasAll,
    unsigned short* __restrict__ hOut,
    const int* __restrict__ rowmap,
    const int* __restrict__ offsets,
    const float* __restrict__ topkw,
    int K, int Ncols, int M2, int MT, int NT) {
  int bid = blockIdx.x;
  int e, mt, nt, rowBase, cnt;
  if (MODE == 2) {
    int nwg = gridDim.x;
    int lg = (bid & 7) * (nwg >> 3) + (bid >> 3);
    e = 0; rowBase = 0; cnt = M2;
    mt = lg / NT; nt = lg % NT;
  } else {
    e = bid & 7;              // expert -> XCD pinning
    int idx = bid >> 3;
    int per = MT * 8;         // one 8-nt band over all mt
    int band = idx / per;
    int r2 = idx - band * per;
    mt = r2 >> 3;
    nt = band * 8 + (r2 & 7);
    rowBase = offsets[e];
    cnt = offsets[e + 1] - rowBase;
    if (mt * 128 >= cnt) return;
  }
  const unsigned short* B = Ball + (size_t)e * Ncols * K;
  const float* bias = biasAll + (size_t)e * Ncols;

  int tid = threadIdx.x;
  int w = tid >> 6, lane = tid & 63;
  int wm = w >> 1, wn = w & 1;

  __shared__ __attribute__((aligned(16))) unsigned short As[3][128][32];
  __shared__ __attribute__((aligned(16))) unsigned short Bs[3][128][32];

  // staging: wave w covers tile rows [w*16, w*16+16) (+64 for 2nd issue);
  // lane covers row w*16 + (lane>>2), 16B chunk (lane&3) of the 64B row slice.
  int li = (w << 4) + (lane >> 2);
  int kb = (lane & 3) * 8;  // element offset

  const unsigned short* asrc[2];
#pragma unroll
  for (int rnd = 0; rnd < 2; ++rnd) {
    int i = li + rnd * 64;
    int r = mt * 128 + i;
    size_t arow;
    if (MODE == 0) {
      int rr = r < cnt ? r : cnt - 1;
      arow = (size_t)(rowmap[rowBase + rr] >> 1);
    } else if (MODE == 1) {
      int rr = r < cnt ? r : cnt - 1;
      arow = (size_t)(rowBase + rr);
    } else {
      arow = (size_t)r;
    }
    asrc[rnd] = A + arow * (size_t)K + kb;
  }
  const unsigned short* bsrc[2];
  bsrc[0] = B + (size_t)(nt * 128 + li) * K + kb;
  bsrc[1] = bsrc[0] + (size_t)64 * K;

  f32x4 acc[4][4] = {};
  int ldsrow = (w << 4);

  auto stage = [&](int buf, int kt) {
    int ko = kt * 32;
    gl_lds16(asrc[0] + ko, &As[buf][ldsrow][0]);
    gl_lds16(asrc[1] + ko, &As[buf][ldsrow + 64][0]);
    gl_lds16(bsrc[0] + ko, &Bs[buf][ldsrow][0]);
    gl_lds16(bsrc[1] + ko, &Bs[buf][ldsrow + 64][0]);
  };

  int KT = K >> 5;
  int fr = lane & 15, fg = lane >> 4;

  // prologue: 2 tiles in flight; enter loop with buf0 landed.
  stage(0, 0);
  stage(1, 1);
  asm volatile("s_waitcnt vmcnt(4)" ::: "memory");
  __builtin_amdgcn_s_barrier();
  __builtin_amdgcn_sched_barrier(0);

  int cur = 0;
  for (int kt = 0; kt < KT; ++kt) {
    // frags from buf[cur] (landed per the invariant)
    s16x8 af[4], bf[4];
#pragma unroll
    for (int m = 0; m < 4; ++m)
      af[m] = *reinterpret_cast<const s16x8*>(&As[cur][wm * 64 + m * 16 + fr][fg * 8]);
#pragma unroll
    for (int n = 0; n < 4; ++n)
      bf[n] = *reinterpret_cast<const s16x8*>(&Bs[cur][wn * 64 + n * 16 + fr][fg * 8]);
    // stage kt+2 into the ring slot last read at iter kt-1
    if (kt + 2 < KT) {
      int nxt = cur + 2; if (nxt >= 3) nxt -= 3;
      stage(nxt, kt + 2);
      // newest 4 loads = stage(kt+2); waiting vmcnt(4) => stage(kt+1) landed
      asm volatile("s_waitcnt vmcnt(4) lgkmcnt(0)" ::: "memory");
    } else {
      asm volatile("s_waitcnt vmcnt(0) lgkmcnt(0)" ::: "memory");
    }
    __builtin_amdgcn_s_barrier();
    __builtin_amdgcn_sched_barrier(0);
#pragma unroll
    for (int m = 0; m < 4; ++m)
#pragma unroll
      for (int n = 0; n < 4; ++n)
        acc[m][n] = __builtin_amdgcn_mfma_f32_16x16x32_bf16(
            __builtin_bit_cast(b16x8, af[m]), __builtin_bit_cast(b16x8, bf[n]),
            acc[m][n], 0, 0, 0);
    cur = cur + 1 < 3 ? cur + 1 : 0;
  }

  // epilogue: C/D layout col=lane&15, row=(lane>>4)*4+q
#pragma unroll
  for (int m = 0; m < 4; ++m) {
#pragma unroll
    for (int q = 0; q < 4; ++q) {
      int rloc = wm * 64 + m * 16 + fg * 4 + q;
      int r = mt * 128 + rloc;
      if (MODE != 2 && r >= cnt) continue;
      if (MODE == 0) {
        size_t orow = (size_t)(rowBase + r) * Ncols;
#pragma unroll
        for (int n = 0; n < 4; ++n) {
          int col = nt * 128 + wn * 64 + n * 16 + fr;
          float v = acc[m][n][q] + bias[col];
          hOut[orow + col] = f2bf(gelu_fast(v));
        }
      } else if (MODE == 1) {
        float wgt = topkw[rowmap[rowBase + r]];
        unsigned short* orow = hOut + (size_t)(rowBase + r) * Ncols;
#pragma unroll
        for (int n = 0; n < 4; ++n) {
          int col = nt * 128 + wn * 64 + n * 16 + fr;
          orow[col] = f2bf(wgt * (acc[m][n][q] + bias[col]));
        }
      } else {
        unsigned short* orow = hOut + (size_t)r * Ncols;
#pragma unroll
        for (int n = 0; n < 4; ++n) {
          int col = nt * 128 + wn * 64 + n * 16 + fr;
          orow[col] = f2bf(0.5f * gelu_fast(acc[m][n][q] + bias[col]));
        }
      }
    }
  }
}

// ---------------- LayerNorm (gathers shared + 2 expert slots, bf16 in) ----
__global__ void ln_kernel(const unsigned short* __restrict__ sh,
                          const unsigned short* __restrict__ acc2,
                          const int* __restrict__ inv,
                          const float* __restrict__ gamma,
                          const float* __restrict__ beta,
                          float* __restrict__ out) {
  int t = blockIdx.x, tid = threadIdx.x;
  int i0 = inv[t * 2 + 0], i1 = inv[t * 2 + 1];
  ushort4 a  = reinterpret_cast<const ushort4*>(sh   + (size_t)t  * DOUT)[tid];
  ushort4 c0 = reinterpret_cast<const ushort4*>(acc2 + (size_t)i0 * DOUT)[tid];
  ushort4 c1 = reinterpret_cast<const ushort4*>(acc2 + (size_t)i1 * DOUT)[tid];
  float4 v;
  v.x = bf2f(a.x) + bf2f(c0.x) + bf2f(c1.x);
  v.y = bf2f(a.y) + bf2f(c0.y) + bf2f(c1.y);
  v.z = bf2f(a.z) + bf2f(c0.z) + bf2f(c1.z);
  v.w = bf2f(a.w) + bf2f(c0.w) + bf2f(c1.w);
  float s = v.x + v.y + v.z + v.w;
  float q = v.x * v.x + v.y * v.y + v.z * v.z + v.w * v.w;
#pragma unroll
  for (int o = 32; o; o >>= 1) {
    s += __shfl_down(s, o);
    q += __shfl_down(q, o);
  }
  __shared__ float ss[4], sq[4];
  int w = tid >> 6, lane = tid & 63;
  if (lane == 0) { ss[w] = s; sq[w] = q; }
  __syncthreads();
  float S = ss[0] + ss[1] + ss[2] + ss[3];
  float Q = sq[0] + sq[1] + sq[2] + sq[3];
  float mean = S * (1.0f / DOUT);
  float var = Q * (1.0f / DOUT) - mean * mean;
  float inv_std = rsqrtf(var + 1e-5f);
  float4 g = reinterpret_cast<const float4*>(gamma)[tid];
  float4 b = reinterpret_cast<const float4*>(beta)[tid];
  float4 o;
  o.x = (v.x - mean) * inv_std * g.x + b.x;
  o.y = (v.y - mean) * inv_std * g.y + b.y;
  o.z = (v.z - mean) * inv_std * g.z + b.z;
  o.w = (v.w - mean) * inv_std * g.w + b.w;
  reinterpret_cast<float4*>(out + (size_t)t * DOUT)[tid] = o;
}

// ---------------- host ----------------
extern "C" void kernel_launch(void* const* d_in, const int* in_sizes, int n_in,
                              void* d_out, int out_size, void* d_ws, size_t ws_size,
                              hipStream_t stream) {
  const float* x       = (const float*)d_in[0];
  const float* W1      = (const float*)d_in[1];
  const float* b1      = (const float*)d_in[2];
  const float* W2      = (const float*)d_in[3];
  const float* b2      = (const float*)d_in[4];
  const float* gateW   = (const float*)d_in[5];
  const float* sharedW = (const float*)d_in[6];
  const float* sharedB = (const float*)d_in[7];
  const float* gamma   = (const float*)d_in[8];
  const float* beta    = (const float*)d_in[9];
  float* out = (float*)d_out;

  char* ws = (char*)d_ws;
  size_t off = 0;
  auto alloc = [&](size_t bytes) -> void* {
    void* p = ws + off;
    off += (bytes + 255) & ~(size_t)255;
    return p;
  };
  int*   counts = (int*)alloc(NEXP * 4);
  int*   offs   = (int*)alloc((NEXP + 1) * 4);
  int*   cursor = (int*)alloc(NEXP * 4);
  int*   topk_e = (int*)alloc((size_t)N_TOK * 2 * 4);
  float* topk_w = (float*)alloc((size_t)N_TOK * 2 * 4);
  int*   rowmap = (int*)alloc((size_t)N_TOK * 2 * 4);
  int*   inv    = (int*)alloc((size_t)N_TOK * 2 * 4);
  unsigned short* xbf  = (unsigned short*)alloc((size_t)N_TOK * DIM * 2);
  unsigned short* W1t  = (unsigned short*)alloc((size_t)NEXP * HID * DIM * 2);
  unsigned short* W2t  = (unsigned short*)alloc((size_t)NEXP * DOUT * HID * 2);
  unsigned short* sWt  = (unsigned short*)alloc((size_t)DOUT * DIM * 2);
  unsigned short* hbuf = (unsigned short*)alloc((size_t)N_TOK * 2 * HID * 2);
  unsigned short* acc2 = (unsigned short*)alloc((size_t)N_TOK * 2 * DOUT * 2);
  // shbuf aliases W1t (W1t dead after GEMM1; shared GEMM launches after it)
  unsigned short* shbuf = W1t;
  if (off > ws_size) return;  // workspace too small -> fail validation loudly

  init_kernel<<<1, 64, 0, stream>>>(counts);
  cast_x_kernel<<<N_TOK * DIM / 1024, 256, 0, stream>>>(x, xbf);
  transpose_cast_kernel<<<dim3(HID / 64, DIM / 64, NEXP), dim3(16, 16), 0, stream>>>(W1, W1t, DIM, HID);
  transpose_cast_kernel<<<dim3(DOUT / 64, HID / 64, NEXP), dim3(16, 16), 0, stream>>>(W2, W2t, HID, DOUT);
  transpose_cast_kernel<<<dim3(DOUT / 64, DIM / 64, 1), dim3(16, 16), 0, stream>>>(sharedW, sWt, DIM, DOUT);
  gate_kernel<<<N_TOK / 4, 256, 0, stream>>>(x, gateW, topk_e, topk_w, counts);
  offsets_kernel<<<1, 64, 0, stream>>>(counts, offs, cursor);
  scatter_kernel<<<N_TOK / 256, 256, 0, stream>>>(topk_e, cursor, rowmap, inv);

  // GEMM1: h = gelu(x @ W1 + b1). MT=32 (cnt>4096 is a >20-sigma event;
  // clamp+early-exit still guard), NT=32.
  gemm_mfma<0><<<NEXP * 32 * (HID / 128), 256, 0, stream>>>(
      xbf, W1t, b1, hbuf, rowmap, offs, topk_w, DIM, HID, 0, 32, HID / 128);
  // shared: shbuf = 0.5*gelu(x @ sharedW + sb)  (bf16)
  gemm_mfma<2><<<(N_TOK / 128) * (DOUT / 128), 256, 0, stream>>>(
      xbf, sWt, sharedB, shbuf, nullptr, nullptr, nullptr, DIM, DOUT,
      N_TOK, N_TOK / 128, DOUT / 128);
  // GEMM2: acc2[slot] = w * (h @ W2 + b2)   (compact, bf16, no atomics)
  gemm_mfma<1><<<NEXP * 32 * (DOUT / 128), 256, 0, stream>>>(
      hbuf, W2t, b2, acc2, rowmap, offs, topk_w, HID, DOUT, 0, 32, DOUT / 128);
  // LayerNorm(shared + slot0 + slot1) -> out
  ln_kernel<<<N_TOK, 256, 0, stream>>>(shbuf, acc2, inv, gamma, beta, out);
}

// Round 7
// 777.734 us; speedup vs baseline: 1.3973x; 1.0033x over previous
//
#include <hip/hip_runtime.h>
#include <cstdint>
#include <cstddef>

#define N_TOK 8192
#define DIM   1024
#define HID   4096
#define DOUT  1024
#define NEXP  8

typedef short  s16x8 __attribute__((ext_vector_type(8)));
typedef __bf16 b16x8 __attribute__((ext_vector_type(8)));
typedef float  f32x4 __attribute__((ext_vector_type(4)));

__device__ __forceinline__ unsigned short f2bf(float f) {
  unsigned u = __float_as_uint(f);
  u += 0x7fffu + ((u >> 16) & 1u);
  return (unsigned short)(u >> 16);
}

__device__ __forceinline__ float bf2f(unsigned short u) {
  return __uint_as_float((unsigned)u << 16);
}

// tanh-form GELU via one fast exp: max |err| vs exact erf-GELU ~3e-4,
// 25x below bf16 quantization of h.
__device__ __forceinline__ float gelu_fast(float v) {
  float u2 = v * (1.5957691216f + 0.0713548163f * v * v);
  return v / (1.0f + __expf(-u2));
}

// async global->LDS, 16B per lane. LDS dest wave-uniform base; HW writes
// lane i at base + i*16. Global src is per-lane.
__device__ __forceinline__ void gl_lds16(const void* g, void* l) {
  auto gp = (__attribute__((address_space(1))) void*)(reinterpret_cast<uintptr_t>(g));
  auto lp = (__attribute__((address_space(3))) void*)(reinterpret_cast<uintptr_t>(l));
  __builtin_amdgcn_global_load_lds(gp, lp, 16, 0, 0);
}

// ---------------- small kernels ----------------

__global__ void init_kernel(int* counts) {
  if (threadIdx.x < NEXP) counts[threadIdx.x] = 0;
}

__global__ void cast_x_kernel(const float* __restrict__ src,
                              unsigned short* __restrict__ dst) {
  int i = blockIdx.x * 256 + threadIdx.x;
  float4 v = reinterpret_cast<const float4*>(src)[i];
  ushort4 o;
  o.x = f2bf(v.x); o.y = f2bf(v.y); o.z = f2bf(v.z); o.w = f2bf(v.w);
  reinterpret_cast<ushort4*>(dst)[i] = o;
}

// src [R][C] f32 (batched by blockIdx.z) -> dst [C][R] bf16.
__global__ void transpose_cast_kernel(const float* __restrict__ src,
                                      unsigned short* __restrict__ dst,
                                      int R, int C) {
  __shared__ float tile[64][65];
  size_t base = (size_t)blockIdx.z * (size_t)R * (size_t)C;
  src += base; dst += base;
  int c0 = blockIdx.x * 64, r0 = blockIdx.y * 64;
  int tx = threadIdx.x, ty = threadIdx.y;  // 16 x 16
#pragma unroll
  for (int i = 0; i < 4; ++i) {
    int r = ty + i * 16;
    float4 v = *reinterpret_cast<const float4*>(src + (size_t)(r0 + r) * C + c0 + tx * 4);
    tile[r][tx * 4 + 0] = v.x;
    tile[r][tx * 4 + 1] = v.y;
    tile[r][tx * 4 + 2] = v.z;
    tile[r][tx * 4 + 3] = v.w;
  }
  __syncthreads();
#pragma unroll
  for (int j = 0; j < 4; ++j) {
    int c = ty + j * 16;
    ushort4 o;
    o.x = f2bf(tile[tx * 4 + 0][c]);
    o.y = f2bf(tile[tx * 4 + 1][c]);
    o.z = f2bf(tile[tx * 4 + 2][c]);
    o.w = f2bf(tile[tx * 4 + 3][c]);
    *reinterpret_cast<ushort4*>(dst + (size_t)(c0 + c) * R + r0 + tx * 4) = o;
  }
}

// one wave per token: f32 gate logits (must stay f32: top-2 selection must
// match the reference's ordering), top-2, renormalized weights
__global__ void gate_kernel(const float* __restrict__ x,
                            const float* __restrict__ gw,
                            int* __restrict__ topk_e,
                            float* __restrict__ topk_w,
                            int* __restrict__ counts) {
  int w = threadIdx.x >> 6, lane = threadIdx.x & 63;
  int t = blockIdx.x * 4 + w;
  const float* xr = x + (size_t)t * DIM;
  float acc[8];
#pragma unroll
  for (int e = 0; e < 8; ++e) acc[e] = 0.f;
  for (int i = 0; i < DIM / 64; ++i) {
    int d = lane + (i << 6);
    float xv = xr[d];
    float4 g0 = *reinterpret_cast<const float4*>(gw + (size_t)d * 8);
    float4 g1 = *reinterpret_cast<const float4*>(gw + (size_t)d * 8 + 4);
    acc[0] += xv * g0.x; acc[1] += xv * g0.y; acc[2] += xv * g0.z; acc[3] += xv * g0.w;
    acc[4] += xv * g1.x; acc[5] += xv * g1.y; acc[6] += xv * g1.z; acc[7] += xv * g1.w;
  }
#pragma unroll
  for (int o = 32; o; o >>= 1)
#pragma unroll
    for (int e = 0; e < 8; ++e) acc[e] += __shfl_down(acc[e], o);
  if (lane == 0) {
    int e0 = 0;
#pragma unroll
    for (int e = 1; e < 8; ++e) if (acc[e] > acc[e0]) e0 = e;
    int e1 = -1;
#pragma unroll
    for (int e = 0; e < 8; ++e) {
      if (e == e0) continue;
      if (e1 < 0 || acc[e] > acc[e1]) e1 = e;
    }
    float w0 = 1.0f / (1.0f + expf(acc[e1] - acc[e0]));  // == p0/(p0+p1)
    topk_e[t * 2 + 0] = e0;
    topk_e[t * 2 + 1] = e1;
    topk_w[t * 2 + 0] = w0;
    topk_w[t * 2 + 1] = 1.0f - w0;
    atomicAdd(&counts[e0], 1);
    atomicAdd(&counts[e1], 1);
  }
}

__global__ void offsets_kernel(const int* __restrict__ counts,
                               int* __restrict__ offsets,
                               int* __restrict__ cursor) {
  if (threadIdx.x == 0) {
    int o = 0;
    for (int e = 0; e < NEXP; ++e) {
      offsets[e] = o; cursor[e] = o; o += counts[e];
    }
    offsets[NEXP] = o;
  }
}

__global__ void scatter_kernel(const int* __restrict__ topk_e,
                               int* __restrict__ cursor,
                               int* __restrict__ rowmap,
                               int* __restrict__ inv) {
  int t = blockIdx.x * 256 + threadIdx.x;
#pragma unroll
  for (int s = 0; s < 2; ++s) {
    int e = topk_e[t * 2 + s];
    int p = atomicAdd(&cursor[e], 1);
    rowmap[p] = t * 2 + s;
    inv[t * 2 + s] = p;
  }
}

// ---------------- MFMA GEMM (256x128 tile, BK=32, 3-buffer ring) ----------
// C[M x ncols] = A[. x K] * Bt[ncols x K], K-contiguous rows.
// 8 waves (4M x 2N), per-wave 64x64 output, acc[4][4] f32x4.
// LDS 72KB (ring-3) -> 2 blocks/CU = 16 waves/CU. Staging 2 K-tiles ahead,
// counted vmcnt(3) (never 0 in the loop) + one raw s_barrier per K-step.
// Ring safety: buf[cur] reads are drained (lgkmcnt(0)) before the iter-kt
// barrier; the overwrite of buf[cur] is stage(kt+3), issued only after a
// wave crosses that barrier.
// Staging: per wave 3 x gl_lds16 -> A rows [32w,32w+32), B rows [16w,16w+16).
// MODE 0: expert GEMM1 (gathered A rows, epi gelu->bf16) PLUS, for
//         bid >= expGrid, the dense shared GEMM (0.5*gelu->bf16) as a
//         trailing block range (fills the GEMM1 tail).
// MODE 1: expert GEMM2, compact A (h), epi: out[slot] = w*(acc+b2) -> bf16
template <int MODE>
__global__ __launch_bounds__(512, 4) void gemm_mfma(
    const unsigned short* __restrict__ A,
    const unsigned short* __restrict__ Ball,
    const float* __restrict__ biasAll,
    unsigned short* __restrict__ outAll,
    const int* __restrict__ rowmap,
    const int* __restrict__ offsets,
    const float* __restrict__ topkw,
    int K, int Ncols, int MT, int NT,
    int expGrid, const unsigned short* __restrict__ sB,
    const float* __restrict__ sBias, unsigned short* __restrict__ sOut,
    int M2) {
  int bid = blockIdx.x;
  int mt, nt, rowBase, cnt, ncols, gath;
  float scale;
  const unsigned short* Bp;
  const float* bias;
  unsigned short* outp;
  if (MODE == 0 && bid >= expGrid) {
    // fused dense shared GEMM, XCD-chunked over its 256 blocks
    int b2 = bid - expGrid;
    int lg = (b2 & 7) * 32 + (b2 >> 3);
    mt = lg >> 3; nt = lg & 7;
    rowBase = 0; cnt = M2; gath = 0; scale = 0.5f;
    Bp = sB; bias = sBias; outp = sOut; ncols = DOUT;
  } else {
    int e = bid & 7;            // expert -> XCD pinning
    int idx = bid >> 3;
    if (MODE == 0) {
      int per = MT * 8;         // 8-nt band over all mt
      int band = idx / per;
      int r2 = idx - band * per;
      mt = r2 >> 3;
      nt = band * 8 + (r2 & 7);
      gath = 2; scale = 1.0f;
    } else {
      mt = idx >> 3; nt = idx & 7;  // NT == 8
      gath = 1; scale = 1.0f;
    }
    rowBase = offsets[e];
    cnt = offsets[e + 1] - rowBase;
    if (mt * 256 >= cnt) return;
    Bp = Ball + (size_t)e * Ncols * K;
    bias = biasAll + (size_t)e * Ncols;
    outp = outAll; ncols = Ncols;
  }

  int t = threadIdx.x;
  int w = t >> 6, lane = t & 63;
  int wm = w >> 1, wn = w & 1;      // 4 x 2 wave grid
  int fr = lane & 15, fg = lane >> 4;

  __shared__ __attribute__((aligned(16))) unsigned short As[3][256][32];
  __shared__ __attribute__((aligned(16))) unsigned short Bs[3][128][32];

  // staging geometry: lane covers row (lane>>2), 16B chunk (lane&3)
  int srow = lane >> 2;
  int kch = (lane & 3) * 8;  // element offset
  int g0 = mt * 256 + w * 32 + srow;
  int g1 = g0 + 16;
  size_t ar0, ar1;
  {
    int c0 = g0 < cnt ? g0 : cnt - 1;
    int c1 = g1 < cnt ? g1 : cnt - 1;
    if (gath == 0)      { ar0 = (size_t)g0;                 ar1 = (size_t)g1; }
    else if (gath == 1) { ar0 = (size_t)(rowBase + c0);     ar1 = (size_t)(rowBase + c1); }
    else                { ar0 = (size_t)(rowmap[rowBase + c0] >> 1);
                          ar1 = (size_t)(rowmap[rowBase + c1] >> 1); }
  }
  const unsigned short* aS0 = A + ar0 * (size_t)K + kch;
  const unsigned short* aS1 = A + ar1 * (size_t)K + kch;
  const unsigned short* bS  = Bp + (size_t)(nt * 128 + w * 16 + srow) * K + kch;

  auto stage = [&](int buf, int kt) {
    int ko = kt * 32;
    gl_lds16(aS0 + ko, &As[buf][w * 32][0]);
    gl_lds16(aS1 + ko, &As[buf][w * 32 + 16][0]);
    gl_lds16(bS + ko, &Bs[buf][w * 16][0]);
  };

  f32x4 acc[4][4] = {};
  int KT = K >> 5;

  // prologue: 2 tiles in flight; enter loop with buf0 landed.
  stage(0, 0);
  stage(1, 1);
  asm volatile("s_waitcnt vmcnt(3)" ::: "memory");
  __builtin_amdgcn_s_barrier();
  __builtin_amdgcn_sched_barrier(0);

  int cur = 0;
  for (int kt = 0; kt < KT; ++kt) {
    s16x8 af[4], bf[4];
#pragma unroll
    for (int m = 0; m < 4; ++m)
      af[m] = *reinterpret_cast<const s16x8*>(&As[cur][wm * 64 + m * 16 + fr][fg * 8]);
#pragma unroll
    for (int n = 0; n < 4; ++n)
      bf[n] = *reinterpret_cast<const s16x8*>(&Bs[cur][wn * 64 + n * 16 + fr][fg * 8]);
    if (kt + 2 < KT) {
      int nxt = cur + 2; if (nxt >= 3) nxt -= 3;
      stage(nxt, kt + 2);
      // newest 3 loads = stage(kt+2); vmcnt(3) => stage(kt+1) landed
      asm volatile("s_waitcnt vmcnt(3) lgkmcnt(0)" ::: "memory");
    } else {
      asm volatile("s_waitcnt vmcnt(0) lgkmcnt(0)" ::: "memory");
    }
    __builtin_amdgcn_s_barrier();
    __builtin_amdgcn_sched_barrier(0);
#pragma unroll
    for (int m = 0; m < 4; ++m)
#pragma unroll
      for (int n = 0; n < 4; ++n)
        acc[m][n] = __builtin_amdgcn_mfma_f32_16x16x32_bf16(
            __builtin_bit_cast(b16x8, af[m]), __builtin_bit_cast(b16x8, bf[n]),
            acc[m][n], 0, 0, 0);
    cur = cur + 1 < 3 ? cur + 1 : 0;
  }

  // epilogue: C/D layout col=lane&15, row=(lane>>4)*4+q
#pragma unroll
  for (int m = 0; m < 4; ++m) {
#pragma unroll
    for (int q = 0; q < 4; ++q) {
      int r = mt * 256 + wm * 64 + m * 16 + fg * 4 + q;
      if (gath != 0 && r >= cnt) continue;
      if (MODE == 1) {
        float wgt = topkw[rowmap[rowBase + r]];
        unsigned short* orow = outp + (size_t)(rowBase + r) * ncols;
#pragma unroll
        for (int n = 0; n < 4; ++n) {
          int col = nt * 128 + wn * 64 + n * 16 + fr;
          orow[col] = f2bf(wgt * (acc[m][n][q] + bias[col]));
        }
      } else {
        size_t orr = (gath ? (size_t)(rowBase + r) : (size_t)r) * (size_t)ncols;
        unsigned short* orow = outp + orr;
#pragma unroll
        for (int n = 0; n < 4; ++n) {
          int col = nt * 128 + wn * 64 + n * 16 + fr;
          orow[col] = f2bf(scale * gelu_fast(acc[m][n][q] + bias[col]));
        }
      }
    }
  }
}

// ---------------- LayerNorm (gathers shared + 2 expert slots, bf16 in) ----
__global__ void ln_kernel(const unsigned short* __restrict__ sh,
                          const unsigned short* __restrict__ acc2,
                          const int* __restrict__ inv,
                          const float* __restrict__ gamma,
                          const float* __restrict__ beta,
                          float* __restrict__ out) {
  int t = blockIdx.x, tid = threadIdx.x;
  int i0 = inv[t * 2 + 0], i1 = inv[t * 2 + 1];
  ushort4 a  = reinterpret_cast<const ushort4*>(sh   + (size_t)t  * DOUT)[tid];
  ushort4 c0 = reinterpret_cast<const ushort4*>(acc2 + (size_t)i0 * DOUT)[tid];
  ushort4 c1 = reinterpret_cast<const ushort4*>(acc2 + (size_t)i1 * DOUT)[tid];
  float4 v;
  v.x = bf2f(a.x) + bf2f(c0.x) + bf2f(c1.x);
  v.y = bf2f(a.y) + bf2f(c0.y) + bf2f(c1.y);
  v.z = bf2f(a.z) + bf2f(c0.z) + bf2f(c1.z);
  v.w = bf2f(a.w) + bf2f(c0.w) + bf2f(c1.w);
  float s = v.x + v.y + v.z + v.w;
  float q = v.x * v.x + v.y * v.y + v.z * v.z + v.w * v.w;
#pragma unroll
  for (int o = 32; o; o >>= 1) {
    s += __shfl_down(s, o);
    q += __shfl_down(q, o);
  }
  __shared__ float ss[4], sq[4];
  int w = tid >> 6, lane = tid & 63;
  if (lane == 0) { ss[w] = s; sq[w] = q; }
  __syncthreads();
  float S = ss[0] + ss[1] + ss[2] + ss[3];
  float Q = sq[0] + sq[1] + sq[2] + sq[3];
  float mean = S * (1.0f / DOUT);
  float var = Q * (1.0f / DOUT) - mean * mean;
  float inv_std = rsqrtf(var + 1e-5f);
  float4 g = reinterpret_cast<const float4*>(gamma)[tid];
  float4 b = reinterpret_cast<const float4*>(beta)[tid];
  float4 o;
  o.x = (v.x - mean) * inv_std * g.x + b.x;
  o.y = (v.y - mean) * inv_std * g.y + b.y;
  o.z = (v.z - mean) * inv_std * g.z + b.z;
  o.w = (v.w - mean) * inv_std * g.w + b.w;
  reinterpret_cast<float4*>(out + (size_t)t * DOUT)[tid] = o;
}

// ---------------- host ----------------
extern "C" void kernel_launch(void* const* d_in, const int* in_sizes, int n_in,
                              void* d_out, int out_size, void* d_ws, size_t ws_size,
                              hipStream_t stream) {
  const float* x       = (const float*)d_in[0];
  const float* W1      = (const float*)d_in[1];
  const float* b1      = (const float*)d_in[2];
  const float* W2      = (const float*)d_in[3];
  const float* b2      = (const float*)d_in[4];
  const float* gateW   = (const float*)d_in[5];
  const float* sharedW = (const float*)d_in[6];
  const float* sharedB = (const float*)d_in[7];
  const float* gamma   = (const float*)d_in[8];
  const float* beta    = (const float*)d_in[9];
  float* out = (float*)d_out;

  char* ws = (char*)d_ws;
  size_t off = 0;
  auto alloc = [&](size_t bytes) -> void* {
    void* p = ws + off;
    off += (bytes + 255) & ~(size_t)255;
    return p;
  };
  int*   counts = (int*)alloc(NEXP * 4);
  int*   offs   = (int*)alloc((NEXP + 1) * 4);
  int*   cursor = (int*)alloc(NEXP * 4);
  int*   topk_e = (int*)alloc((size_t)N_TOK * 2 * 4);
  float* topk_w = (float*)alloc((size_t)N_TOK * 2 * 4);
  int*   rowmap = (int*)alloc((size_t)N_TOK * 2 * 4);
  int*   inv    = (int*)alloc((size_t)N_TOK * 2 * 4);
  unsigned short* xbf  = (unsigned short*)alloc((size_t)N_TOK * DIM * 2);
  unsigned short* W1t  = (unsigned short*)alloc((size_t)NEXP * HID * DIM * 2);
  unsigned short* W2t  = (unsigned short*)alloc((size_t)NEXP * DOUT * HID * 2);
  unsigned short* sWt  = (unsigned short*)alloc((size_t)DOUT * DIM * 2);
  unsigned short* hbuf = (unsigned short*)alloc((size_t)N_TOK * 2 * HID * 2);
  unsigned short* acc2 = (unsigned short*)alloc((size_t)N_TOK * 2 * DOUT * 2);
  // shbuf is its own buffer now: shared GEMM runs fused with GEMM1, which
  // still reads W1t -> aliasing would race.
  unsigned short* shbuf = (unsigned short*)alloc((size_t)N_TOK * DOUT * 2);
  if (off > ws_size) return;  // workspace too small -> fail validation loudly

  init_kernel<<<1, 64, 0, stream>>>(counts);
  cast_x_kernel<<<N_TOK * DIM / 1024, 256, 0, stream>>>(x, xbf);
  transpose_cast_kernel<<<dim3(HID / 64, DIM / 64, NEXP), dim3(16, 16), 0, stream>>>(W1, W1t, DIM, HID);
  transpose_cast_kernel<<<dim3(DOUT / 64, HID / 64, NEXP), dim3(16, 16), 0, stream>>>(W2, W2t, HID, DOUT);
  transpose_cast_kernel<<<dim3(DOUT / 64, DIM / 64, 1), dim3(16, 16), 0, stream>>>(sharedW, sWt, DIM, DOUT);
  gate_kernel<<<N_TOK / 4, 256, 0, stream>>>(x, gateW, topk_e, topk_w, counts);
  offsets_kernel<<<1, 64, 0, stream>>>(counts, offs, cursor);
  scatter_kernel<<<N_TOK / 256, 256, 0, stream>>>(topk_e, cursor, rowmap, inv);

  // GEMM1 (experts, MT=16 x NT=32 per expert) + fused shared GEMM tail
  // (32 mt x 8 nt = 256 blocks). expGrid = 8*16*32 = 4096.
  gemm_mfma<0><<<NEXP * 16 * (HID / 128) + (N_TOK / 256) * (DOUT / 128), 512, 0, stream>>>(
      xbf, W1t, b1, hbuf, rowmap, offs, topk_w, DIM, HID, 16, HID / 128,
      NEXP * 16 * (HID / 128), sWt, sharedB, shbuf, N_TOK);
  // GEMM2: acc2[slot] = w * (h @ W2 + b2)   (compact, bf16, no atomics)
  gemm_mfma<1><<<NEXP * 16 * (DOUT / 128), 512, 0, stream>>>(
      hbuf, W2t, b2, acc2, rowmap, offs, topk_w, HID, DOUT, 16, DOUT / 128,
      0, nullptr, nullptr, nullptr, 0);
  // LayerNorm(shared + slot0 + slot1) -> out
  ln_kernel<<<N_TOK, 256, 0, stream>>>(shbuf, acc2, inv, gamma, beta, out);
}

// Round 8
// 764.795 us; speedup vs baseline: 1.4209x; 1.0169x over previous
//
#include <hip/hip_runtime.h>
#include <cstdint>
#include <cstddef>

#define N_TOK 8192
#define DIM   1024
#define HID   4096
#define DOUT  1024
#define NEXP  8

typedef short  s16x8 __attribute__((ext_vector_type(8)));
typedef __bf16 b16x8 __attribute__((ext_vector_type(8)));
typedef float  f32x4 __attribute__((ext_vector_type(4)));

__device__ __forceinline__ unsigned short f2bf(float f) {
  unsigned u = __float_as_uint(f);
  u += 0x7fffu + ((u >> 16) & 1u);
  return (unsigned short)(u >> 16);
}

__device__ __forceinline__ float bf2f(unsigned short u) {
  return __uint_as_float((unsigned)u << 16);
}

// tanh-form GELU via one fast exp: max |err| vs exact erf-GELU ~3e-4,
// 25x below bf16 quantization of h.
__device__ __forceinline__ float gelu_fast(float v) {
  float u2 = v * (1.5957691216f + 0.0713548163f * v * v);
  return v / (1.0f + __expf(-u2));
}

// async global->LDS, 16B per lane. LDS dest wave-uniform base; HW writes
// lane i at base + i*16. Global src is per-lane (enables source pre-swizzle).
__device__ __forceinline__ void gl_lds16(const void* g, void* l) {
  auto gp = (__attribute__((address_space(1))) void*)(reinterpret_cast<uintptr_t>(g));
  auto lp = (__attribute__((address_space(3))) void*)(reinterpret_cast<uintptr_t>(l));
  __builtin_amdgcn_global_load_lds(gp, lp, 16, 0, 0);
}

// ---------------- small kernels ----------------

__global__ void init_kernel(int* counts) {
  if (threadIdx.x < NEXP) counts[threadIdx.x] = 0;
}

// src [R][C] f32 (batched by blockIdx.z) -> dst [C][R] bf16.
__global__ void transpose_cast_kernel(const float* __restrict__ src,
                                      unsigned short* __restrict__ dst,
                                      int R, int C) {
  __shared__ float tile[64][65];
  size_t base = (size_t)blockIdx.z * (size_t)R * (size_t)C;
  src += base; dst += base;
  int c0 = blockIdx.x * 64, r0 = blockIdx.y * 64;
  int tx = threadIdx.x, ty = threadIdx.y;  // 16 x 16
#pragma unroll
  for (int i = 0; i < 4; ++i) {
    int r = ty + i * 16;
    float4 v = *reinterpret_cast<const float4*>(src + (size_t)(r0 + r) * C + c0 + tx * 4);
    tile[r][tx * 4 + 0] = v.x;
    tile[r][tx * 4 + 1] = v.y;
    tile[r][tx * 4 + 2] = v.z;
    tile[r][tx * 4 + 3] = v.w;
  }
  __syncthreads();
#pragma unroll
  for (int j = 0; j < 4; ++j) {
    int c = ty + j * 16;
    ushort4 o;
    o.x = f2bf(tile[tx * 4 + 0][c]);
    o.y = f2bf(tile[tx * 4 + 1][c]);
    o.z = f2bf(tile[tx * 4 + 2][c]);
    o.w = f2bf(tile[tx * 4 + 3][c]);
    *reinterpret_cast<ushort4*>(dst + (size_t)(c0 + c) * R + r0 + tx * 4) = o;
  }
}

// one wave per token: f32 gate logits (f32 kept: top-2 selection must match
// the reference ordering), top-2, renormalized weights. Also emits x as bf16
// (fused cast: x rows are already in registers).
__global__ void gate_kernel(const float* __restrict__ x,
                            const float* __restrict__ gw,
                            unsigned short* __restrict__ xbf,
                            int* __restrict__ topk_e,
                            float* __restrict__ topk_w,
                            int* __restrict__ counts) {
  int w = threadIdx.x >> 6, lane = threadIdx.x & 63;
  int t = blockIdx.x * 4 + w;
  const float* xr = x + (size_t)t * DIM;
  unsigned short* xo = xbf + (size_t)t * DIM;
  float acc[8];
#pragma unroll
  for (int e = 0; e < 8; ++e) acc[e] = 0.f;
  for (int i = 0; i < DIM / 64; ++i) {
    int d = lane + (i << 6);
    float xv = xr[d];
    xo[d] = f2bf(xv);
    float4 g0 = *reinterpret_cast<const float4*>(gw + (size_t)d * 8);
    float4 g1 = *reinterpret_cast<const float4*>(gw + (size_t)d * 8 + 4);
    acc[0] += xv * g0.x; acc[1] += xv * g0.y; acc[2] += xv * g0.z; acc[3] += xv * g0.w;
    acc[4] += xv * g1.x; acc[5] += xv * g1.y; acc[6] += xv * g1.z; acc[7] += xv * g1.w;
  }
#pragma unroll
  for (int o = 32; o; o >>= 1)
#pragma unroll
    for (int e = 0; e < 8; ++e) acc[e] += __shfl_down(acc[e], o);
  if (lane == 0) {
    int e0 = 0;
#pragma unroll
    for (int e = 1; e < 8; ++e) if (acc[e] > acc[e0]) e0 = e;
    int e1 = -1;
#pragma unroll
    for (int e = 0; e < 8; ++e) {
      if (e == e0) continue;
      if (e1 < 0 || acc[e] > acc[e1]) e1 = e;
    }
    float w0 = 1.0f / (1.0f + expf(acc[e1] - acc[e0]));  // == p0/(p0+p1)
    topk_e[t * 2 + 0] = e0;
    topk_e[t * 2 + 1] = e1;
    topk_w[t * 2 + 0] = w0;
    topk_w[t * 2 + 1] = 1.0f - w0;
    atomicAdd(&counts[e0], 1);
    atomicAdd(&counts[e1], 1);
  }
}

__global__ void offsets_kernel(const int* __restrict__ counts,
                               int* __restrict__ offsets,
                               int* __restrict__ cursor) {
  if (threadIdx.x == 0) {
    int o = 0;
    for (int e = 0; e < NEXP; ++e) {
      offsets[e] = o; cursor[e] = o; o += counts[e];
    }
    offsets[NEXP] = o;
  }
}

__global__ void scatter_kernel(const int* __restrict__ topk_e,
                               int* __restrict__ cursor,
                               int* __restrict__ rowmap,
                               int* __restrict__ inv) {
  int t = blockIdx.x * 256 + threadIdx.x;
#pragma unroll
  for (int s = 0; s < 2; ++s) {
    int e = topk_e[t * 2 + s];
    int p = atomicAdd(&cursor[e], 1);
    rowmap[p] = t * 2 + s;
    inv[t * 2 + s] = p;
  }
}

// ---------------- MFMA GEMM (256x128 tile, BK=32, 3-buffer ring, T2+T5) ---
// C[M x ncols] = A[. x K] * Bt[ncols x K], K-contiguous rows.
// 8 waves (4M x 2N), per-wave 64x64 output, acc[4][4] f32x4.
// LDS 72KB (ring-3) -> 2 blocks/CU = 16 waves/CU. Staging 2 K-tiles ahead,
// counted vmcnt(3) (never 0 in the loop) + one raw s_barrier per K-step.
// T2 LDS swizzle (both-sides, rule #21): physical 16B-chunk = logical chunk
// ^ ((row>>1)&3). Write side: gl_lds writes lane l linearly at chunk (l&3)
// of row base+(l>>2), so the per-lane GLOBAL source is pre-inverse-swizzled
// (logical chunk (l&3)^((l>>3)&3)). Read side: fragment chunk fg is read at
// physical chunk fg^((fr>>1)&3). R3 measured this zeroes SQ_LDS_BANK_CONFLICT
// on exactly this [rows][32-elem] geometry.
// T5: setprio(1) around the 16-MFMA cluster.
// MODE 0: expert GEMM1 (gathered A rows, epi gelu->bf16) PLUS, for
//         bid >= expGrid, the dense shared GEMM (0.5*gelu->bf16) tail.
// MODE 1: expert GEMM2, compact A (h), epi: out[slot] = w*(acc+b2) -> bf16
template <int MODE>
__global__ __launch_bounds__(512, 4) void gemm_mfma(
    const unsigned short* __restrict__ A,
    const unsigned short* __restrict__ Ball,
    const float* __restrict__ biasAll,
    unsigned short* __restrict__ outAll,
    const int* __restrict__ rowmap,
    const int* __restrict__ offsets,
    const float* __restrict__ topkw,
    int K, int Ncols, int MT, int NT,
    int expGrid, const unsigned short* __restrict__ sB,
    const float* __restrict__ sBias, unsigned short* __restrict__ sOut,
    int M2) {
  int bid = blockIdx.x;
  int mt, nt, rowBase, cnt, ncols, gath;
  float scale;
  const unsigned short* Bp;
  const float* bias;
  unsigned short* outp;
  if (MODE == 0 && bid >= expGrid) {
    // fused dense shared GEMM, XCD-chunked over its 256 blocks
    int b2 = bid - expGrid;
    int lg = (b2 & 7) * 32 + (b2 >> 3);
    mt = lg >> 3; nt = lg & 7;
    rowBase = 0; cnt = M2; gath = 0; scale = 0.5f;
    Bp = sB; bias = sBias; outp = sOut; ncols = DOUT;
  } else {
    int e = bid & 7;            // expert -> XCD pinning
    int idx = bid >> 3;
    if (MODE == 0) {
      int per = MT * 8;         // 8-nt band over all mt
      int band = idx / per;
      int r2 = idx - band * per;
      mt = r2 >> 3;
      nt = band * 8 + (r2 & 7);
      gath = 2; scale = 1.0f;
    } else {
      mt = idx >> 3; nt = idx & 7;  // NT == 8
      gath = 1; scale = 1.0f;
    }
    rowBase = offsets[e];
    cnt = offsets[e + 1] - rowBase;
    if (mt * 256 >= cnt) return;
    Bp = Ball + (size_t)e * Ncols * K;
    bias = biasAll + (size_t)e * Ncols;
    outp = outAll; ncols = Ncols;
  }

  int t = threadIdx.x;
  int w = t >> 6, lane = t & 63;
  int wm = w >> 1, wn = w & 1;      // 4 x 2 wave grid
  int fr = lane & 15, fg = lane >> 4;

  __shared__ __attribute__((aligned(16))) unsigned short As[3][256][32];
  __shared__ __attribute__((aligned(16))) unsigned short Bs[3][128][32];

  // staging geometry: lane covers row (lane>>2); physical chunk (lane&3)
  // receives logical chunk (lane&3)^((lane>>3)&3)  [= (l&3)^((row>>1)&3)].
  int srow = lane >> 2;
  int kch = ((lane & 3) ^ ((lane >> 3) & 3)) * 8;  // element offset (swz)
  int g0 = mt * 256 + w * 32 + srow;
  int g1 = g0 + 16;
  size_t ar0, ar1;
  {
    int c0 = g0 < cnt ? g0 : cnt - 1;
    int c1 = g1 < cnt ? g1 : cnt - 1;
    if (gath == 0)      { ar0 = (size_t)g0;                 ar1 = (size_t)g1; }
    else if (gath == 1) { ar0 = (size_t)(rowBase + c0);     ar1 = (size_t)(rowBase + c1); }
    else                { ar0 = (size_t)(rowmap[rowBase + c0] >> 1);
                          ar1 = (size_t)(rowmap[rowBase + c1] >> 1); }
  }
  const unsigned short* aS0 = A + ar0 * (size_t)K + kch;
  const unsigned short* aS1 = A + ar1 * (size_t)K + kch;
  const unsigned short* bS  = Bp + (size_t)(nt * 128 + w * 16 + srow) * K + kch;

  auto stage = [&](int buf, int kt) {
    int ko = kt * 32;
    gl_lds16(aS0 + ko, &As[buf][w * 32][0]);
    gl_lds16(aS1 + ko, &As[buf][w * 32 + 16][0]);
    gl_lds16(bS + ko, &Bs[buf][w * 16][0]);
  };

  f32x4 acc[4][4] = {};
  int KT = K >> 5;
  int swc = (fg ^ ((fr >> 1) & 3)) * 8;  // swizzled read chunk (elements)

  // prologue: 2 tiles in flight; enter loop with buf0 landed.
  stage(0, 0);
  stage(1, 1);
  asm volatile("s_waitcnt vmcnt(3)" ::: "memory");
  __builtin_amdgcn_s_barrier();
  __builtin_amdgcn_sched_barrier(0);

  int cur = 0;
  for (int kt = 0; kt < KT; ++kt) {
    s16x8 af[4], bf[4];
#pragma unroll
    for (int m = 0; m < 4; ++m)
      af[m] = *reinterpret_cast<const s16x8*>(&As[cur][wm * 64 + m * 16 + fr][swc]);
#pragma unroll
    for (int n = 0; n < 4; ++n)
      bf[n] = *reinterpret_cast<const s16x8*>(&Bs[cur][wn * 64 + n * 16 + fr][swc]);
    if (kt + 2 < KT) {
      int nxt = cur + 2; if (nxt >= 3) nxt -= 3;
      stage(nxt, kt + 2);
      // newest 3 loads = stage(kt+2); vmcnt(3) => stage(kt+1) landed
      asm volatile("s_waitcnt vmcnt(3) lgkmcnt(0)" ::: "memory");
    } else {
      asm volatile("s_waitcnt vmcnt(0) lgkmcnt(0)" ::: "memory");
    }
    __builtin_amdgcn_s_barrier();
    __builtin_amdgcn_sched_barrier(0);
    __builtin_amdgcn_s_setprio(1);
#pragma unroll
    for (int m = 0; m < 4; ++m)
#pragma unroll
      for (int n = 0; n < 4; ++n)
        acc[m][n] = __builtin_amdgcn_mfma_f32_16x16x32_bf16(
            __builtin_bit_cast(b16x8, af[m]), __builtin_bit_cast(b16x8, bf[n]),
            acc[m][n], 0, 0, 0);
    __builtin_amdgcn_s_setprio(0);
    cur = cur + 1 < 3 ? cur + 1 : 0;
  }

  // epilogue: C/D layout col=lane&15, row=(lane>>4)*4+q
#pragma unroll
  for (int m = 0; m < 4; ++m) {
#pragma unroll
    for (int q = 0; q < 4; ++q) {
      int r = mt * 256 + wm * 64 + m * 16 + fg * 4 + q;
      if (gath != 0 && r >= cnt) continue;
      if (MODE == 1) {
        float wgt = topkw[rowmap[rowBase + r]];
        unsigned short* orow = outp + (size_t)(rowBase + r) * ncols;
#pragma unroll
        for (int n = 0; n < 4; ++n) {
          int col = nt * 128 + wn * 64 + n * 16 + fr;
          orow[col] = f2bf(wgt * (acc[m][n][q] + bias[col]));
        }
      } else {
        size_t orr = (gath ? (size_t)(rowBase + r) : (size_t)r) * (size_t)ncols;
        unsigned short* orow = outp + orr;
#pragma unroll
        for (int n = 0; n < 4; ++n) {
          int col = nt * 128 + wn * 64 + n * 16 + fr;
          orow[col] = f2bf(scale * gelu_fast(acc[m][n][q] + bias[col]));
        }
      }
    }
  }
}

// ---------------- LayerNorm (gathers shared + 2 expert slots, bf16 in) ----
__global__ void ln_kernel(const unsigned short* __restrict__ sh,
                          const unsigned short* __restrict__ acc2,
                          const int* __restrict__ inv,
                          const float* __restrict__ gamma,
                          const float* __restrict__ beta,
                          float* __restrict__ out) {
  int t = blockIdx.x, tid = threadIdx.x;
  int i0 = inv[t * 2 + 0], i1 = inv[t * 2 + 1];
  ushort4 a  = reinterpret_cast<const ushort4*>(sh   + (size_t)t  * DOUT)[tid];
  ushort4 c0 = reinterpret_cast<const ushort4*>(acc2 + (size_t)i0 * DOUT)[tid];
  ushort4 c1 = reinterpret_cast<const ushort4*>(acc2 + (size_t)i1 * DOUT)[tid];
  float4 v;
  v.x = bf2f(a.x) + bf2f(c0.x) + bf2f(c1.x);
  v.y = bf2f(a.y) + bf2f(c0.y) + bf2f(c1.y);
  v.z = bf2f(a.z) + bf2f(c0.z) + bf2f(c1.z);
  v.w = bf2f(a.w) + bf2f(c0.w) + bf2f(c1.w);
  float s = v.x + v.y + v.z + v.w;
  float q = v.x * v.x + v.y * v.y + v.z * v.z + v.w * v.w;
#pragma unroll
  for (int o = 32; o; o >>= 1) {
    s += __shfl_down(s, o);
    q += __shfl_down(q, o);
  }
  __shared__ float ss[4], sq[4];
  int w = tid >> 6, lane = tid & 63;
  if (lane == 0) { ss[w] = s; sq[w] = q; }
  __syncthreads();
  float S = ss[0] + ss[1] + ss[2] + ss[3];
  float Q = sq[0] + sq[1] + sq[2] + sq[3];
  float mean = S * (1.0f / DOUT);
  float var = Q * (1.0f / DOUT) - mean * mean;
  float inv_std = rsqrtf(var + 1e-5f);
  float4 g = reinterpret_cast<const float4*>(gamma)[tid];
  float4 b = reinterpret_cast<const float4*>(beta)[tid];
  float4 o;
  o.x = (v.x - mean) * inv_std * g.x + b.x;
  o.y = (v.y - mean) * inv_std * g.y + b.y;
  o.z = (v.z - mean) * inv_std * g.z + b.z;
  o.w = (v.w - mean) * inv_std * g.w + b.w;
  reinterpret_cast<float4*>(out + (size_t)t * DOUT)[tid] = o;
}

// ---------------- host ----------------
extern "C" void kernel_launch(void* const* d_in, const int* in_sizes, int n_in,
                              void* d_out, int out_size, void* d_ws, size_t ws_size,
                              hipStream_t stream) {
  const float* x       = (const float*)d_in[0];
  const float* W1      = (const float*)d_in[1];
  const float* b1      = (const float*)d_in[2];
  const float* W2      = (const float*)d_in[3];
  const float* b2      = (const float*)d_in[4];
  const float* gateW   = (const float*)d_in[5];
  const float* sharedW = (const float*)d_in[6];
  const float* sharedB = (const float*)d_in[7];
  const float* gamma   = (const float*)d_in[8];
  const float* beta    = (const float*)d_in[9];
  float* out = (float*)d_out;

  char* ws = (char*)d_ws;
  size_t off = 0;
  auto alloc = [&](size_t bytes) -> void* {
    void* p = ws + off;
    off += (bytes + 255) & ~(size_t)255;
    return p;
  };
  int*   counts = (int*)alloc(NEXP * 4);
  int*   offs   = (int*)alloc((NEXP + 1) * 4);
  int*   cursor = (int*)alloc(NEXP * 4);
  int*   topk_e = (int*)alloc((size_t)N_TOK * 2 * 4);
  float* topk_w = (float*)alloc((size_t)N_TOK * 2 * 4);
  int*   rowmap = (int*)alloc((size_t)N_TOK * 2 * 4);
  int*   inv    = (int*)alloc((size_t)N_TOK * 2 * 4);
  unsigned short* xbf  = (unsigned short*)alloc((size_t)N_TOK * DIM * 2);
  unsigned short* W1t  = (unsigned short*)alloc((size_t)NEXP * HID * DIM * 2);
  unsigned short* W2t  = (unsigned short*)alloc((size_t)NEXP * DOUT * HID * 2);
  unsigned short* sWt  = (unsigned short*)alloc((size_t)DOUT * DIM * 2);
  unsigned short* hbuf = (unsigned short*)alloc((size_t)N_TOK * 2 * HID * 2);
  unsigned short* acc2 = (unsigned short*)alloc((size_t)N_TOK * 2 * DOUT * 2);
  // shbuf: own buffer (shared GEMM runs fused with GEMM1, which reads W1t)
  unsigned short* shbuf = (unsigned short*)alloc((size_t)N_TOK * DOUT * 2);
  if (off > ws_size) return;  // workspace too small -> fail validation loudly

  init_kernel<<<1, 64, 0, stream>>>(counts);
  transpose_cast_kernel<<<dim3(HID / 64, DIM / 64, NEXP), dim3(16, 16), 0, stream>>>(W1, W1t, DIM, HID);
  transpose_cast_kernel<<<dim3(DOUT / 64, HID / 64, NEXP), dim3(16, 16), 0, stream>>>(W2, W2t, HID, DOUT);
  transpose_cast_kernel<<<dim3(DOUT / 64, DIM / 64, 1), dim3(16, 16), 0, stream>>>(sharedW, sWt, DIM, DOUT);
  gate_kernel<<<N_TOK / 4, 256, 0, stream>>>(x, gateW, xbf, topk_e, topk_w, counts);
  offsets_kernel<<<1, 64, 0, stream>>>(counts, offs, cursor);
  scatter_kernel<<<N_TOK / 256, 256, 0, stream>>>(topk_e, cursor, rowmap, inv);

  // GEMM1 (experts, MT=16 x NT=32 per expert) + fused shared GEMM tail
  // (32 mt x 8 nt = 256 blocks). expGrid = 8*16*32 = 4096.
  gemm_mfma<0><<<NEXP * 16 * (HID / 128) + (N_TOK / 256) * (DOUT / 128), 512, 0, stream>>>(
      xbf, W1t, b1, hbuf, rowmap, offs, topk_w, DIM, HID, 16, HID / 128,
      NEXP * 16 * (HID / 128), sWt, sharedB, shbuf, N_TOK);
  // GEMM2: acc2[slot] = w * (h @ W2 + b2)   (compact, bf16, no atomics)
  gemm_mfma<1><<<NEXP * 16 * (DOUT / 128), 512, 0, stream>>>(
      hbuf, W2t, b2, acc2, rowmap, offs, topk_w, HID, DOUT, 16, DOUT / 128,
      0, nullptr, nullptr, nullptr, 0);
  // LayerNorm(shared + slot0 + slot1) -> out
  ln_kernel<<<N_TOK, 256, 0, stream>>>(shbuf, acc2, inv, gamma, beta, out);
}

// Round 9
// 755.698 us; speedup vs baseline: 1.4381x; 1.0120x over previous
//
#include <hip/hip_runtime.h>
#include <cstdint>
#include <cstddef>

#define N_TOK 8192
#define DIM   1024
#define HID   4096
#define DOUT  1024
#define NEXP  8

typedef short  s16x8 __attribute__((ext_vector_type(8)));
typedef __bf16 b16x8 __attribute__((ext_vector_type(8)));
typedef float  f32x4 __attribute__((ext_vector_type(4)));

__device__ __forceinline__ unsigned short f2bf(float f) {
  unsigned u = __float_as_uint(f);
  u += 0x7fffu + ((u >> 16) & 1u);
  return (unsigned short)(u >> 16);
}

__device__ __forceinline__ float bf2f(unsigned short u) {
  return __uint_as_float((unsigned)u << 16);
}

// tanh-form GELU via one fast exp: max |err| vs exact erf-GELU ~3e-4,
// 25x below bf16 quantization of h.
__device__ __forceinline__ float gelu_fast(float v) {
  float u2 = v * (1.5957691216f + 0.0713548163f * v * v);
  return v / (1.0f + __expf(-u2));
}

// async global->LDS, 16B per lane. LDS dest wave-uniform base; HW writes
// lane i at base + i*16. Global src is per-lane (enables source pre-swizzle).
__device__ __forceinline__ void gl_lds16(const void* g, void* l) {
  auto gp = (__attribute__((address_space(1))) void*)(reinterpret_cast<uintptr_t>(g));
  auto lp = (__attribute__((address_space(3))) void*)(reinterpret_cast<uintptr_t>(l));
  __builtin_amdgcn_global_load_lds(gp, lp, 16, 0, 0);
}

// ---------------- small kernels ----------------

__global__ void init_kernel(int* counts) {
  if (threadIdx.x < NEXP) counts[threadIdx.x] = 0;
}

// src [R][C] f32 (batched by blockIdx.z) -> dst [C][R] bf16.
__global__ void transpose_cast_kernel(const float* __restrict__ src,
                                      unsigned short* __restrict__ dst,
                                      int R, int C) {
  __shared__ float tile[64][65];
  size_t base = (size_t)blockIdx.z * (size_t)R * (size_t)C;
  src += base; dst += base;
  int c0 = blockIdx.x * 64, r0 = blockIdx.y * 64;
  int tx = threadIdx.x, ty = threadIdx.y;  // 16 x 16
#pragma unroll
  for (int i = 0; i < 4; ++i) {
    int r = ty + i * 16;
    float4 v = *reinterpret_cast<const float4*>(src + (size_t)(r0 + r) * C + c0 + tx * 4);
    tile[r][tx * 4 + 0] = v.x;
    tile[r][tx * 4 + 1] = v.y;
    tile[r][tx * 4 + 2] = v.z;
    tile[r][tx * 4 + 3] = v.w;
  }
  __syncthreads();
#pragma unroll
  for (int j = 0; j < 4; ++j) {
    int c = ty + j * 16;
    ushort4 o;
    o.x = f2bf(tile[tx * 4 + 0][c]);
    o.y = f2bf(tile[tx * 4 + 1][c]);
    o.z = f2bf(tile[tx * 4 + 2][c]);
    o.w = f2bf(tile[tx * 4 + 3][c]);
    *reinterpret_cast<ushort4*>(dst + (size_t)(c0 + c) * R + r0 + tx * 4) = o;
  }
}

// one wave per token: f32 gate logits (f32 kept: top-2 selection must match
// the reference ordering), top-2, renormalized weights. Also emits x as bf16
// (fused cast: x rows are already in registers).
__global__ void gate_kernel(const float* __restrict__ x,
                            const float* __restrict__ gw,
                            unsigned short* __restrict__ xbf,
                            int* __restrict__ topk_e,
                            float* __restrict__ topk_w,
                            int* __restrict__ counts) {
  int w = threadIdx.x >> 6, lane = threadIdx.x & 63;
  int t = blockIdx.x * 4 + w;
  const float* xr = x + (size_t)t * DIM;
  unsigned short* xo = xbf + (size_t)t * DIM;
  float acc[8];
#pragma unroll
  for (int e = 0; e < 8; ++e) acc[e] = 0.f;
  for (int i = 0; i < DIM / 64; ++i) {
    int d = lane + (i << 6);
    float xv = xr[d];
    xo[d] = f2bf(xv);
    float4 g0 = *reinterpret_cast<const float4*>(gw + (size_t)d * 8);
    float4 g1 = *reinterpret_cast<const float4*>(gw + (size_t)d * 8 + 4);
    acc[0] += xv * g0.x; acc[1] += xv * g0.y; acc[2] += xv * g0.z; acc[3] += xv * g0.w;
    acc[4] += xv * g1.x; acc[5] += xv * g1.y; acc[6] += xv * g1.z; acc[7] += xv * g1.w;
  }
#pragma unroll
  for (int o = 32; o; o >>= 1)
#pragma unroll
    for (int e = 0; e < 8; ++e) acc[e] += __shfl_down(acc[e], o);
  if (lane == 0) {
    int e0 = 0;
#pragma unroll
    for (int e = 1; e < 8; ++e) if (acc[e] > acc[e0]) e0 = e;
    int e1 = -1;
#pragma unroll
    for (int e = 0; e < 8; ++e) {
      if (e == e0) continue;
      if (e1 < 0 || acc[e] > acc[e1]) e1 = e;
    }
    float w0 = 1.0f / (1.0f + expf(acc[e1] - acc[e0]));  // == p0/(p0+p1)
    topk_e[t * 2 + 0] = e0;
    topk_e[t * 2 + 1] = e1;
    topk_w[t * 2 + 0] = w0;
    topk_w[t * 2 + 1] = 1.0f - w0;
    atomicAdd(&counts[e0], 1);
    atomicAdd(&counts[e1], 1);
  }
}

__global__ void offsets_kernel(const int* __restrict__ counts,
                               int* __restrict__ offsets,
                               int* __restrict__ cursor) {
  if (threadIdx.x == 0) {
    int o = 0;
    for (int e = 0; e < NEXP; ++e) {
      offsets[e] = o; cursor[e] = o; o += counts[e];
    }
    offsets[NEXP] = o;
  }
}

__global__ void scatter_kernel(const int* __restrict__ topk_e,
                               int* __restrict__ cursor,
                               int* __restrict__ rowmap,
                               int* __restrict__ inv) {
  int t = blockIdx.x * 256 + threadIdx.x;
#pragma unroll
  for (int s = 0; s < 2; ++s) {
    int e = topk_e[t * 2 + s];
    int p = atomicAdd(&cursor[e], 1);
    rowmap[p] = t * 2 + s;
    inv[t * 2 + s] = p;
  }
}

// ---------------- MFMA GEMM (256x128 tile, BK=32, 3-buffer ring, T2+T5) ---
// C[M x ncols] = A[. x K] * Bt[ncols x K], K-contiguous rows.
// 8 waves (4M x 2N), per-wave 64x64 output, acc[4][4] f32x4.
// LDS 72KB (ring-3) -> 2 blocks/CU = 16 waves/CU. Staging 2 K-tiles ahead,
// counted vmcnt(3) (never 0 in the loop) + one raw s_barrier per K-step.
// R9: no sched_barrier / no lgkmcnt between reads and MFMA — ds_read->MFMA
// ordering is register dataflow; the compiler emits fine-grained lgkmcnt so
// MFMA starts as frags arrive (m97 behavior). Ring/WAR safety moves to a
// single trailing "vmcnt(3) lgkmcnt(0); s_barrier" per iteration:
//   - lgkmcnt(0) drains this wave's buf[cur] reads before the barrier that
//     permits iter kt+1's stage to overwrite buf[cur];
//   - vmcnt(3) proves stage(kt+1) landed before anyone reads it.
// Memory ops cannot cross the "memory"-clobber asm, so nothing leaks.
// T2 LDS swizzle (both-sides, rule #21): physical 16B-chunk = logical chunk
// ^ ((row>>1)&3); write side via pre-inverse-swizzled global source, read
// side via fg^((fr>>1)&3). Measured: zeroes SQ_LDS_BANK_CONFLICT (R8).
// T5: setprio(1) around the MFMA cluster.
// MODE 0: expert GEMM1 (gathered A rows, epi gelu->bf16) PLUS, for
//         bid >= expGrid, the dense shared GEMM (0.5*gelu->bf16) tail.
// MODE 1: expert GEMM2, compact A (h), epi: out[slot] = w*(acc+b2) -> bf16
template <int MODE>
__global__ __launch_bounds__(512, 4) void gemm_mfma(
    const unsigned short* __restrict__ A,
    const unsigned short* __restrict__ Ball,
    const float* __restrict__ biasAll,
    unsigned short* __restrict__ outAll,
    const int* __restrict__ rowmap,
    const int* __restrict__ offsets,
    const float* __restrict__ topkw,
    int K, int Ncols, int MT, int NT,
    int expGrid, const unsigned short* __restrict__ sB,
    const float* __restrict__ sBias, unsigned short* __restrict__ sOut,
    int M2) {
  int bid = blockIdx.x;
  int mt, nt, rowBase, cnt, ncols, gath;
  float scale;
  const unsigned short* Bp;
  const float* bias;
  unsigned short* outp;
  if (MODE == 0 && bid >= expGrid) {
    // fused dense shared GEMM, XCD-chunked over its 256 blocks
    int b2 = bid - expGrid;
    int lg = (b2 & 7) * 32 + (b2 >> 3);
    mt = lg >> 3; nt = lg & 7;
    rowBase = 0; cnt = M2; gath = 0; scale = 0.5f;
    Bp = sB; bias = sBias; outp = sOut; ncols = DOUT;
  } else {
    int e = bid & 7;            // expert -> XCD pinning
    int idx = bid >> 3;
    if (MODE == 0) {
      int per = MT * 8;         // 8-nt band over all mt
      int band = idx / per;
      int r2 = idx - band * per;
      mt = r2 >> 3;
      nt = band * 8 + (r2 & 7);
      gath = 2; scale = 1.0f;
    } else {
      mt = idx >> 3; nt = idx & 7;  // NT == 8
      gath = 1; scale = 1.0f;
    }
    rowBase = offsets[e];
    cnt = offsets[e + 1] - rowBase;
    if (mt * 256 >= cnt) return;
    Bp = Ball + (size_t)e * Ncols * K;
    bias = biasAll + (size_t)e * Ncols;
    outp = outAll; ncols = Ncols;
  }

  int t = threadIdx.x;
  int w = t >> 6, lane = t & 63;
  int wm = w >> 1, wn = w & 1;      // 4 x 2 wave grid
  int fr = lane & 15, fg = lane >> 4;

  __shared__ __attribute__((aligned(16))) unsigned short As[3][256][32];
  __shared__ __attribute__((aligned(16))) unsigned short Bs[3][128][32];

  // staging geometry: lane covers row (lane>>2); physical chunk (lane&3)
  // receives logical chunk (lane&3)^((lane>>3)&3)  [= (l&3)^((row>>1)&3)].
  int srow = lane >> 2;
  int kch = ((lane & 3) ^ ((lane >> 3) & 3)) * 8;  // element offset (swz)
  int g0 = mt * 256 + w * 32 + srow;
  int g1 = g0 + 16;
  size_t ar0, ar1;
  {
    int c0 = g0 < cnt ? g0 : cnt - 1;
    int c1 = g1 < cnt ? g1 : cnt - 1;
    if (gath == 0)      { ar0 = (size_t)g0;                 ar1 = (size_t)g1; }
    else if (gath == 1) { ar0 = (size_t)(rowBase + c0);     ar1 = (size_t)(rowBase + c1); }
    else                { ar0 = (size_t)(rowmap[rowBase + c0] >> 1);
                          ar1 = (size_t)(rowmap[rowBase + c1] >> 1); }
  }
  const unsigned short* aS0 = A + ar0 * (size_t)K + kch;
  const unsigned short* aS1 = A + ar1 * (size_t)K + kch;
  const unsigned short* bS  = Bp + (size_t)(nt * 128 + w * 16 + srow) * K + kch;

  auto stage = [&](int buf, int kt) {
    int ko = kt * 32;
    gl_lds16(aS0 + ko, &As[buf][w * 32][0]);
    gl_lds16(aS1 + ko, &As[buf][w * 32 + 16][0]);
    gl_lds16(bS + ko, &Bs[buf][w * 16][0]);
  };

  f32x4 acc[4][4] = {};
  int KT = K >> 5;
  int swc = (fg ^ ((fr >> 1) & 3)) * 8;  // swizzled read chunk (elements)

  // prologue: 2 tiles in flight; enter loop with buf0 landed.
  stage(0, 0);
  stage(1, 1);
  asm volatile("s_waitcnt vmcnt(3)" ::: "memory");
  __builtin_amdgcn_s_barrier();

  int cur = 0;
  for (int kt = 0; kt < KT; ++kt) {
    // issue next-next stage first: HBM latency starts earliest
    if (kt + 2 < KT) {
      int nxt = cur + 2; if (nxt >= 3) nxt -= 3;
      stage(nxt, kt + 2);
    }
    // fragment reads from buf[cur]; MFMA ordering via dataflow (compiler
    // emits fine-grained lgkmcnt, interleaving reads with MFMAs)
    s16x8 af[4], bf[4];
#pragma unroll
    for (int m = 0; m < 4; ++m)
      af[m] = *reinterpret_cast<const s16x8*>(&As[cur][wm * 64 + m * 16 + fr][swc]);
#pragma unroll
    for (int n = 0; n < 4; ++n)
      bf[n] = *reinterpret_cast<const s16x8*>(&Bs[cur][wn * 64 + n * 16 + fr][swc]);
    __builtin_amdgcn_s_setprio(1);
#pragma unroll
    for (int m = 0; m < 4; ++m)
#pragma unroll
      for (int n = 0; n < 4; ++n)
        acc[m][n] = __builtin_amdgcn_mfma_f32_16x16x32_bf16(
            __builtin_bit_cast(b16x8, af[m]), __builtin_bit_cast(b16x8, bf[n]),
            acc[m][n], 0, 0, 0);
    __builtin_amdgcn_s_setprio(0);
    // single trailing fence: my LDS reads drained (WAR vs next stage) and
    // stage(kt+1) landed (RAW for next iter). Never vmcnt(0) mid-loop.
    if (kt + 2 < KT)
      asm volatile("s_waitcnt vmcnt(3) lgkmcnt(0)" ::: "memory");
    else
      asm volatile("s_waitcnt vmcnt(0) lgkmcnt(0)" ::: "memory");
    __builtin_amdgcn_s_barrier();
    cur = cur + 1 < 3 ? cur + 1 : 0;
  }

  // epilogue: C/D layout col=lane&15, row=(lane>>4)*4+q
#pragma unroll
  for (int m = 0; m < 4; ++m) {
#pragma unroll
    for (int q = 0; q < 4; ++q) {
      int r = mt * 256 + wm * 64 + m * 16 + fg * 4 + q;
      if (gath != 0 && r >= cnt) continue;
      if (MODE == 1) {
        float wgt = topkw[rowmap[rowBase + r]];
        unsigned short* orow = outp + (size_t)(rowBase + r) * ncols;
#pragma unroll
        for (int n = 0; n < 4; ++n) {
          int col = nt * 128 + wn * 64 + n * 16 + fr;
          orow[col] = f2bf(wgt * (acc[m][n][q] + bias[col]));
        }
      } else {
        size_t orr = (gath ? (size_t)(rowBase + r) : (size_t)r) * (size_t)ncols;
        unsigned short* orow = outp + orr;
#pragma unroll
        for (int n = 0; n < 4; ++n) {
          int col = nt * 128 + wn * 64 + n * 16 + fr;
          orow[col] = f2bf(scale * gelu_fast(acc[m][n][q] + bias[col]));
        }
      }
    }
  }
}

// ---------------- LayerNorm (gathers shared + 2 expert slots, bf16 in) ----
__global__ void ln_kernel(const unsigned short* __restrict__ sh,
                          const unsigned short* __restrict__ acc2,
                          const int* __restrict__ inv,
                          const float* __restrict__ gamma,
                          const float* __restrict__ beta,
                          float* __restrict__ out) {
  int t = blockIdx.x, tid = threadIdx.x;
  int i0 = inv[t * 2 + 0], i1 = inv[t * 2 + 1];
  ushort4 a  = reinterpret_cast<const ushort4*>(sh   + (size_t)t  * DOUT)[tid];
  ushort4 c0 = reinterpret_cast<const ushort4*>(acc2 + (size_t)i0 * DOUT)[tid];
  ushort4 c1 = reinterpret_cast<const ushort4*>(acc2 + (size_t)i1 * DOUT)[tid];
  float4 v;
  v.x = bf2f(a.x) + bf2f(c0.x) + bf2f(c1.x);
  v.y = bf2f(a.y) + bf2f(c0.y) + bf2f(c1.y);
  v.z = bf2f(a.z) + bf2f(c0.z) + bf2f(c1.z);
  v.w = bf2f(a.w) + bf2f(c0.w) + bf2f(c1.w);
  float s = v.x + v.y + v.z + v.w;
  float q = v.x * v.x + v.y * v.y + v.z * v.z + v.w * v.w;
#pragma unroll
  for (int o = 32; o; o >>= 1) {
    s += __shfl_down(s, o);
    q += __shfl_down(q, o);
  }
  __shared__ float ss[4], sq[4];
  int w = tid >> 6, lane = tid & 63;
  if (lane == 0) { ss[w] = s; sq[w] = q; }
  __syncthreads();
  float S = ss[0] + ss[1] + ss[2] + ss[3];
  float Q = sq[0] + sq[1] + sq[2] + sq[3];
  float mean = S * (1.0f / DOUT);
  float var = Q * (1.0f / DOUT) - mean * mean;
  float inv_std = rsqrtf(var + 1e-5f);
  float4 g = reinterpret_cast<const float4*>(gamma)[tid];
  float4 b = reinterpret_cast<const float4*>(beta)[tid];
  float4 o;
  o.x = (v.x - mean) * inv_std * g.x + b.x;
  o.y = (v.y - mean) * inv_std * g.y + b.y;
  o.z = (v.z - mean) * inv_std * g.z + b.z;
  o.w = (v.w - mean) * inv_std * g.w + b.w;
  reinterpret_cast<float4*>(out + (size_t)t * DOUT)[tid] = o;
}

// ---------------- host ----------------
extern "C" void kernel_launch(void* const* d_in, const int* in_sizes, int n_in,
                              void* d_out, int out_size, void* d_ws, size_t ws_size,
                              hipStream_t stream) {
  const float* x       = (const float*)d_in[0];
  const float* W1      = (const float*)d_in[1];
  const float* b1      = (const float*)d_in[2];
  const float* W2      = (const float*)d_in[3];
  const float* b2      = (const float*)d_in[4];
  const float* gateW   = (const float*)d_in[5];
  const float* sharedW = (const float*)d_in[6];
  const float* sharedB = (const float*)d_in[7];
  const float* gamma   = (const float*)d_in[8];
  const float* beta    = (const float*)d_in[9];
  float* out = (float*)d_out;

  char* ws = (char*)d_ws;
  size_t off = 0;
  auto alloc = [&](size_t bytes) -> void* {
    void* p = ws + off;
    off += (bytes + 255) & ~(size_t)255;
    return p;
  };
  int*   counts = (int*)alloc(NEXP * 4);
  int*   offs   = (int*)alloc((NEXP + 1) * 4);
  int*   cursor = (int*)alloc(NEXP * 4);
  int*   topk_e = (int*)alloc((size_t)N_TOK * 2 * 4);
  float* topk_w = (float*)alloc((size_t)N_TOK * 2 * 4);
  int*   rowmap = (int*)alloc((size_t)N_TOK * 2 * 4);
  int*   inv    = (int*)alloc((size_t)N_TOK * 2 * 4);
  unsigned short* xbf  = (unsigned short*)alloc((size_t)N_TOK * DIM * 2);
  unsigned short* W1t  = (unsigned short*)alloc((size_t)NEXP * HID * DIM * 2);
  unsigned short* W2t  = (unsigned short*)alloc((size_t)NEXP * DOUT * HID * 2);
  unsigned short* sWt  = (unsigned short*)alloc((size_t)DOUT * DIM * 2);
  unsigned short* hbuf = (unsigned short*)alloc((size_t)N_TOK * 2 * HID * 2);
  unsigned short* acc2 = (unsigned short*)alloc((size_t)N_TOK * 2 * DOUT * 2);
  // shbuf: own buffer (shared GEMM runs fused with GEMM1, which reads W1t)
  unsigned short* shbuf = (unsigned short*)alloc((size_t)N_TOK * DOUT * 2);
  if (off > ws_size) return;  // workspace too small -> fail validation loudly

  init_kernel<<<1, 64, 0, stream>>>(counts);
  transpose_cast_kernel<<<dim3(HID / 64, DIM / 64, NEXP), dim3(16, 16), 0, stream>>>(W1, W1t, DIM, HID);
  transpose_cast_kernel<<<dim3(DOUT / 64, HID / 64, NEXP), dim3(16, 16), 0, stream>>>(W2, W2t, HID, DOUT);
  transpose_cast_kernel<<<dim3(DOUT / 64, DIM / 64, 1), dim3(16, 16), 0, stream>>>(sharedW, sWt, DIM, DOUT);
  gate_kernel<<<N_TOK / 4, 256, 0, stream>>>(x, gateW, xbf, topk_e, topk_w, counts);
  offsets_kernel<<<1, 64, 0, stream>>>(counts, offs, cursor);
  scatter_kernel<<<N_TOK / 256, 256, 0, stream>>>(topk_e, cursor, rowmap, inv);

  // GEMM1 (experts, MT=16 x NT=32 per expert) + fused shared GEMM tail
  // (32 mt x 8 nt = 256 blocks). expGrid = 8*16*32 = 4096.
  gemm_mfma<0><<<NEXP * 16 * (HID / 128) + (N_TOK / 256) * (DOUT / 128), 512, 0, stream>>>(
      xbf, W1t, b1, hbuf, rowmap, offs, topk_w, DIM, HID, 16, HID / 128,
      NEXP * 16 * (HID / 128), sWt, sharedB, shbuf, N_TOK);
  // GEMM2: acc2[slot] = w * (h @ W2 + b2)   (compact, bf16, no atomics)
  gemm_mfma<1><<<NEXP * 16 * (DOUT / 128), 512, 0, stream>>>(
      hbuf, W2t, b2, acc2, rowmap, offs, topk_w, HID, DOUT, 16, DOUT / 128,
      0, nullptr, nullptr, nullptr, 0);
  // LayerNorm(shared + slot0 + slot1) -> out
  ln_kernel<<<N_TOK, 256, 0, stream>>>(shbuf, acc2, inv, gamma, beta, out);
}